// Round 1
// baseline (780.288 us; speedup 1.0000x reference)
//
#include <hip/hip_runtime.h>
#include <hip/hip_bf16.h>
#include <math.h>

// ---------------- elementwise: h0 = x + pe (pe[:4] flattened == first 128 floats) ----------------
__global__ void k_pe(const float* __restrict__ x, const float* __restrict__ pe,
                     float* __restrict__ h, int total) {
  int i = blockIdx.x * blockDim.x + threadIdx.x;
  if (i < total) {
    int f = i & 127;
    h[i] = x[i] + pe[f];
  }
}

// ---------------- CSR build ----------------
__global__ void k_hist(const int* __restrict__ ei, int E, int* __restrict__ cnt) {
  int e = blockIdx.x * blockDim.x + threadIdx.x;
  if (e < E) atomicAdd(cnt + ei[E + e], 1);  // row 1 = dst
}

__global__ __launch_bounds__(1024) void k_scan(int* cntA, int* offsA, int* cntB, int* offsB, int N) {
  int* cnt  = blockIdx.x ? cntB  : cntA;   // counts in, cursor out (in place)
  int* offs = blockIdx.x ? offsB : offsA;
  __shared__ int wsum[16];
  __shared__ int s_carry, s_total;
  const int t = threadIdx.x, lane = t & 63, wid = t >> 6;
  if (t == 0) s_carry = 0;
  __syncthreads();
  for (int base = 0; base < N; base += 1024) {
    int i = base + t;
    int v = (i < N) ? cnt[i] : 0;
    int incl = v;
    #pragma unroll
    for (int d = 1; d < 64; d <<= 1) {
      int u = __shfl_up(incl, d, 64);
      if (lane >= d) incl += u;
    }
    if (lane == 63) wsum[wid] = incl;
    __syncthreads();
    if (wid == 0) {
      int ws = (lane < 16) ? wsum[lane] : 0;
      int wi = ws;
      #pragma unroll
      for (int d = 1; d < 16; d <<= 1) {
        int u = __shfl_up(wi, d, 64);
        if (lane >= d) wi += u;
      }
      if (lane < 16) wsum[lane] = wi - ws;  // exclusive wave prefix
      if (lane == 15) s_total = wi;
    }
    __syncthreads();
    int excl = s_carry + wsum[wid] + (incl - v);
    if (i < N) { offs[i] = excl; cnt[i] = excl; }
    __syncthreads();
    if (t == 0) s_carry += s_total;
    __syncthreads();
  }
  if (t == 0) offs[N] = s_carry;
}

__global__ void k_fill(const int* __restrict__ ei, const float* __restrict__ ew, int E,
                       int* __restrict__ cur, int* __restrict__ srcs, float* __restrict__ wts) {
  int e = blockIdx.x * blockDim.x + threadIdx.x;
  if (e < E) {
    int pos = atomicAdd(cur + ei[E + e], 1);
    srcs[pos] = ei[e];
    wts[pos]  = ew[e];
  }
}

// ---------------- weight prep: Wcat0 = [Wmi0+Ws0 | Wmo0+Ws0] (128x256); Wcat1 = [Wmi1+Ws1 | Wmo1+Ws1 | resW] (128x192)
__global__ void k_wprep(const float* __restrict__ Wmi0, const float* __restrict__ Wmo0, const float* __restrict__ Ws0,
                        const float* __restrict__ Wmi1, const float* __restrict__ Wmo1, const float* __restrict__ Ws1,
                        const float* __restrict__ resW,
                        float* __restrict__ Wcat0, float* __restrict__ Wcat1) {
  int i = blockIdx.x * blockDim.x + threadIdx.x;
  if (i < 128 * 256) {
    int k = i >> 8, n = i & 255;
    float v = (n < 128) ? (Wmi0[k * 128 + n] + Ws0[k * 128 + n])
                        : (Wmo0[k * 128 + n - 128] + Ws0[k * 128 + n - 128]);
    Wcat0[i] = v;
  }
  if (i < 128 * 192) {
    int k = i / 192, n = i % 192;
    float v;
    if (n < 64)       v = Wmi1[k * 64 + n]       + Ws1[k * 64 + n];
    else if (n < 128) v = Wmo1[k * 64 + n - 64]  + Ws1[k * 64 + n - 64];
    else              v = resW[k * 64 + n - 128];
    Wcat1[k * 192 + n] = v;
  }
}

// ---------------- GEMM: C[N x DO] = A[N x 128] @ W[128 x DO], 64x64 tile, 4x4 per thread ----------------
__global__ __launch_bounds__(256) void k_gemm(const float* __restrict__ A,
                                              const float* __restrict__ W,
                                              float* __restrict__ C, int N, int DO) {
  __shared__ float As[64][68];  // [m][k-chunk], pad 4: 2-way-free reads
  __shared__ float Bs[64][68];  // [k][n]
  const int t  = threadIdx.x;
  const int bm = blockIdx.x * 64;
  const int bn = blockIdx.y * 64;
  const int tx = t & 15, ty = t >> 4;
  const int sr = t >> 4;          // 0..15
  const int sc = (t & 15) * 4;    // 0..60
  float acc[4][4] = {};
  for (int kc = 0; kc < 128; kc += 64) {
    __syncthreads();
    #pragma unroll
    for (int j = 0; j < 4; ++j) {
      int r = j * 16 + sr;
      int gm = bm + r;
      float4 v = make_float4(0.f, 0.f, 0.f, 0.f);
      if (gm < N) v = *(const float4*)(A + (size_t)gm * 128 + kc + sc);
      *(float4*)(&As[r][sc]) = v;
      *(float4*)(&Bs[r][sc]) = *(const float4*)(W + (size_t)(kc + r) * DO + bn + sc);
    }
    __syncthreads();
    #pragma unroll 8
    for (int k = 0; k < 64; ++k) {
      float a0 = As[ty * 4 + 0][k];
      float a1 = As[ty * 4 + 1][k];
      float a2 = As[ty * 4 + 2][k];
      float a3 = As[ty * 4 + 3][k];
      float4 b = *(const float4*)(&Bs[k][tx * 4]);
      acc[0][0] = fmaf(a0, b.x, acc[0][0]); acc[0][1] = fmaf(a0, b.y, acc[0][1]);
      acc[0][2] = fmaf(a0, b.z, acc[0][2]); acc[0][3] = fmaf(a0, b.w, acc[0][3]);
      acc[1][0] = fmaf(a1, b.x, acc[1][0]); acc[1][1] = fmaf(a1, b.y, acc[1][1]);
      acc[1][2] = fmaf(a1, b.z, acc[1][2]); acc[1][3] = fmaf(a1, b.w, acc[1][3]);
      acc[2][0] = fmaf(a2, b.x, acc[2][0]); acc[2][1] = fmaf(a2, b.y, acc[2][1]);
      acc[2][2] = fmaf(a2, b.z, acc[2][2]); acc[2][3] = fmaf(a2, b.w, acc[2][3]);
      acc[3][0] = fmaf(a3, b.x, acc[3][0]); acc[3][1] = fmaf(a3, b.y, acc[3][1]);
      acc[3][2] = fmaf(a3, b.z, acc[3][2]); acc[3][3] = fmaf(a3, b.w, acc[3][3]);
    }
  }
  #pragma unroll
  for (int i = 0; i < 4; ++i) {
    int gm = bm + ty * 4 + i;
    if (gm < N) {
      float4 v = make_float4(acc[i][0], acc[i][1], acc[i][2], acc[i][3]);
      *(float4*)(C + (size_t)gm * DO + bn + tx * 4) = v;
    }
  }
}

// ---------------- pull aggregation, 128 cols (2 per lane), one wave per node ----------------
__global__ __launch_bounds__(256) void k_agg2(const float* __restrict__ T, int tstride, int coloff,
                                              const int* __restrict__ offs, const int* __restrict__ srcs,
                                              const float* __restrict__ wts,
                                              float* __restrict__ out, int ostride, int ooff, int N) {
  int n = (blockIdx.x * blockDim.x + threadIdx.x) >> 6;
  int lane = threadIdx.x & 63;
  if (n >= N) return;
  int s0 = offs[n], s1 = offs[n + 1];
  const float* base = T + coloff + lane * 2;
  float a0 = 0.f, a1 = 0.f;
  int i = s0;
  for (; i + 2 <= s1; i += 2) {
    int   sA = srcs[i], sB = srcs[i + 1];
    float wA = wts[i],  wB = wts[i + 1];
    float2 vA = *(const float2*)(base + (size_t)sA * tstride);
    float2 vB = *(const float2*)(base + (size_t)sB * tstride);
    a0 += wA * vA.x + wB * vB.x;
    a1 += wA * vA.y + wB * vB.y;
  }
  if (i < s1) {
    int sA = srcs[i]; float wA = wts[i];
    float2 vA = *(const float2*)(base + (size_t)sA * tstride);
    a0 += wA * vA.x; a1 += wA * vA.y;
  }
  *(float2*)(out + (size_t)n * ostride + ooff + lane * 2) = make_float2(a0, a1);
}

// ---------------- pull aggregation, 64 cols (1 per lane) ----------------
__global__ __launch_bounds__(256) void k_agg1(const float* __restrict__ T, int tstride, int coloff,
                                              const int* __restrict__ offs, const int* __restrict__ srcs,
                                              const float* __restrict__ wts,
                                              float* __restrict__ out, int ostride, int ooff, int N) {
  int n = (blockIdx.x * blockDim.x + threadIdx.x) >> 6;
  int lane = threadIdx.x & 63;
  if (n >= N) return;
  int s0 = offs[n], s1 = offs[n + 1];
  const float* base = T + coloff + lane;
  float a0 = 0.f;
  int i = s0;
  for (; i + 2 <= s1; i += 2) {
    int   sA = srcs[i], sB = srcs[i + 1];
    float wA = wts[i],  wB = wts[i + 1];
    a0 += wA * base[(size_t)sA * tstride] + wB * base[(size_t)sB * tstride];
  }
  if (i < s1) a0 += wts[i] * base[(size_t)srcs[i] * tstride];
  out[(size_t)n * ostride + ooff + lane] = a0;
}

// ---------------- h1 = tanh(cin*(aggin+bmi+bsi) + cout*(aggout+bmo+bso) + h0), in place ----------------
__global__ void k_h1(float* __restrict__ h, const float* __restrict__ agg,
                     const float* __restrict__ bmi, const float* __restrict__ bsi,
                     const float* __restrict__ bmo, const float* __restrict__ bso,
                     const float* __restrict__ cin, const float* __restrict__ cou, int N) {
  int i = blockIdx.x * blockDim.x + threadIdx.x;
  if (i >= N * 128) return;
  int n = i >> 7, f = i & 127;
  float ic = agg[(size_t)n * 256 + f]       + bmi[f] + bsi[f];
  float oc = agg[(size_t)n * 256 + 128 + f] + bmo[f] + bso[f];
  h[i] = tanhf(cin[n] * ic + cou[n] * oc + h[i]);
}

// ---------------- h2 = tanh(cin*(aggin+b) + cout*(aggout+b) + res + resb) ----------------
__global__ void k_h2(float* __restrict__ h2, const float* __restrict__ agg,
                     const float* __restrict__ tres,  // t1 + 128, row stride 192
                     const float* __restrict__ bmi, const float* __restrict__ bsi,
                     const float* __restrict__ bmo, const float* __restrict__ bso,
                     const float* __restrict__ resb,
                     const float* __restrict__ cin, const float* __restrict__ cou, int N) {
  int i = blockIdx.x * blockDim.x + threadIdx.x;
  if (i >= N * 64) return;
  int n = i >> 6, f = i & 63;
  float ic = agg[(size_t)n * 128 + f]      + bmi[f] + bsi[f];
  float oc = agg[(size_t)n * 128 + 64 + f] + bmo[f] + bso[f];
  float r  = tres[(size_t)n * 192 + f] + resb[f];
  h2[i] = tanhf(cin[n] * ic + cou[n] * oc + r);
}

// ---------------- decoder + log_softmax + L2-normalized embedding, one wave per node ----------------
__global__ __launch_bounds__(256) void k_dec(const float* __restrict__ h2,
                                             const float* __restrict__ Wd, const float* __restrict__ bd,
                                             float* __restrict__ logp, float* __restrict__ emb, int N) {
  __shared__ float sW[64 * 128];
  __shared__ float sb[128];
  const int t = threadIdx.x;
  #pragma unroll
  for (int j = 0; j < 8; ++j) {
    int idx = (j * 256 + t) * 4;
    *(float4*)(sW + idx) = *(const float4*)(Wd + idx);
  }
  if (t < 128) sb[t] = bd[t];
  __syncthreads();
  const int lane = t & 63;
  const int n = blockIdx.x * 4 + (t >> 6);
  if (n >= N) return;
  float hv = h2[(size_t)n * 64 + lane];
  float acc0 = 0.f, acc1 = 0.f;
  #pragma unroll 16
  for (int k = 0; k < 64; ++k) {
    float hk = __shfl(hv, k, 64);
    acc0 = fmaf(hk, sW[k * 128 + lane], acc0);
    acc1 = fmaf(hk, sW[k * 128 + 64 + lane], acc1);
  }
  float l0 = acc0 + sb[lane];
  float l1 = acc1 + sb[64 + lane];
  float m = fmaxf(l0, l1);
  #pragma unroll
  for (int d = 32; d > 0; d >>= 1) m = fmaxf(m, __shfl_xor(m, d, 64));
  float s = __expf(l0 - m) + __expf(l1 - m);
  #pragma unroll
  for (int d = 32; d > 0; d >>= 1) s += __shfl_xor(s, d, 64);
  float lse = m + __logf(s);
  logp[(size_t)n * 128 + lane]      = l0 - lse;
  logp[(size_t)n * 128 + 64 + lane] = l1 - lse;
  float q = hv * hv;
  #pragma unroll
  for (int d = 32; d > 0; d >>= 1) q += __shfl_xor(q, d, 64);
  emb[(size_t)n * 64 + lane] = hv / (sqrtf(q) + 1e-12f);
}

extern "C" void kernel_launch(void* const* d_in, const int* in_sizes, int n_in,
                              void* d_out, int out_size, void* d_ws, size_t ws_size,
                              hipStream_t stream) {
  const float* x     = (const float*)d_in[0];
  const int*   ei_in = (const int*)d_in[1];
  const float* ew_in = (const float*)d_in[2];
  const int*   ei_ou = (const int*)d_in[3];
  const float* ew_ou = (const float*)d_in[4];
  const float* pe    = (const float*)d_in[5];
  const float* Wmi0  = (const float*)d_in[6];
  const float* Wmo0  = (const float*)d_in[7];
  const float* Wsh0  = (const float*)d_in[8];
  const float* bmi0  = (const float*)d_in[9];
  const float* bmo0  = (const float*)d_in[10];
  const float* bsi0  = (const float*)d_in[11];
  const float* bso0  = (const float*)d_in[12];
  const float* cin0  = (const float*)d_in[13];
  const float* cou0  = (const float*)d_in[14];
  const float* Wmi1  = (const float*)d_in[15];
  const float* Wmo1  = (const float*)d_in[16];
  const float* Wsh1  = (const float*)d_in[17];
  const float* bmi1  = (const float*)d_in[18];
  const float* bmo1  = (const float*)d_in[19];
  const float* bsi1  = (const float*)d_in[20];
  const float* bso1  = (const float*)d_in[21];
  const float* cin1  = (const float*)d_in[22];
  const float* cou1  = (const float*)d_in[23];
  const float* resW  = (const float*)d_in[24];
  const float* resb  = (const float*)d_in[25];
  const float* Wd    = (const float*)d_in[26];
  const float* bd    = (const float*)d_in[27];

  const int N = in_sizes[0] / 128;
  const int E = in_sizes[2];

  char* ws = (char*)d_ws;
  size_t off = 0;
  auto alloc = [&](size_t bytes) -> char* {
    off = (off + 255) & ~(size_t)255;
    char* p = ws + off;
    off += bytes;
    return p;
  };
  float* hbuf   = (float*)alloc((size_t)N * 128 * 4);  // h0 -> h1 (in place) -> h2 (overlay)
  float* tbuf   = (float*)alloc((size_t)N * 256 * 4);  // t0 (N x 256) -> t1 (N x 192)
  float* aggbuf = (float*)alloc((size_t)N * 256 * 4);  // agg0 (N x 256) -> agg1 (N x 128)
  float* Wcat0  = (float*)alloc(128 * 256 * 4);
  float* Wcat1  = (float*)alloc(128 * 192 * 4);
  int*   offsI  = (int*)alloc((size_t)(N + 1) * 4);
  int*   curI   = (int*)alloc((size_t)N * 4);
  int*   srcsI  = (int*)alloc((size_t)E * 4);
  float* wtsI   = (float*)alloc((size_t)E * 4);
  int*   offsO  = (int*)alloc((size_t)(N + 1) * 4);
  int*   curO   = (int*)alloc((size_t)N * 4);
  int*   srcsO  = (int*)alloc((size_t)E * 4);
  float* wtsO   = (float*)alloc((size_t)E * 4);
  float* h2buf  = hbuf;  // overlay: h1 dead after gemm1 (residual carried inside t1)

  (void)hipMemsetAsync(curI, 0, (size_t)N * 4, stream);
  (void)hipMemsetAsync(curO, 0, (size_t)N * 4, stream);

  const int eb = (E + 255) / 256;
  k_pe<<<(N * 128 + 255) / 256, 256, 0, stream>>>(x, pe, hbuf, N * 128);
  k_hist<<<eb, 256, 0, stream>>>(ei_in, E, curI);
  k_hist<<<eb, 256, 0, stream>>>(ei_ou, E, curO);
  k_scan<<<2, 1024, 0, stream>>>(curI, offsI, curO, offsO, N);
  k_fill<<<eb, 256, 0, stream>>>(ei_in, ew_in, E, curI, srcsI, wtsI);
  k_fill<<<eb, 256, 0, stream>>>(ei_ou, ew_ou, E, curO, srcsO, wtsO);
  k_wprep<<<(128 * 256 + 255) / 256, 256, 0, stream>>>(Wmi0, Wmo0, Wsh0, Wmi1, Wmo1, Wsh1, resW, Wcat0, Wcat1);

  dim3 g0((N + 63) / 64, 4);
  k_gemm<<<g0, 256, 0, stream>>>(hbuf, Wcat0, tbuf, N, 256);
  int ab = (N + 3) / 4;
  k_agg2<<<ab, 256, 0, stream>>>(tbuf, 256, 0,   offsI, srcsI, wtsI, aggbuf, 256, 0,   N);
  k_agg2<<<ab, 256, 0, stream>>>(tbuf, 256, 128, offsO, srcsO, wtsO, aggbuf, 256, 128, N);
  k_h1<<<(N * 128 + 255) / 256, 256, 0, stream>>>(hbuf, aggbuf, bmi0, bsi0, bmo0, bso0, cin0, cou0, N);

  dim3 g1((N + 63) / 64, 3);
  k_gemm<<<g1, 256, 0, stream>>>(hbuf, Wcat1, tbuf, N, 192);
  k_agg1<<<ab, 256, 0, stream>>>(tbuf, 192, 0,  offsI, srcsI, wtsI, aggbuf, 128, 0,  N);
  k_agg1<<<ab, 256, 0, stream>>>(tbuf, 192, 64, offsO, srcsO, wtsO, aggbuf, 128, 64, N);
  k_h2<<<(N * 64 + 255) / 256, 256, 0, stream>>>(h2buf, aggbuf, tbuf + 128,
                                                 bmi1, bsi1, bmo1, bso1, resb, cin1, cou1, N);

  float* logp = (float*)d_out;
  float* emb  = logp + (size_t)N * 128;
  k_dec<<<(N + 3) / 4, 256, 0, stream>>>(h2buf, Wd, bd, logp, emb, N);
}

// Round 2
// 744.798 us; speedup vs baseline: 1.0477x; 1.0477x over previous
//
#include <hip/hip_runtime.h>
#include <hip/hip_bf16.h>
#include <math.h>

// ---------------- elementwise: h0 = x + pe (pe[:4] flattened == first 128 floats) ----------------
__global__ void k_pe(const float* __restrict__ x, const float* __restrict__ pe,
                     float* __restrict__ h, int total) {
  int i = blockIdx.x * blockDim.x + threadIdx.x;
  if (i < total) {
    int f = i & 127;
    h[i] = x[i] + pe[f];
  }
}

// ---------------- CSR build ----------------
__global__ void k_hist(const int* __restrict__ ei, int E, int* __restrict__ cnt) {
  int e = blockIdx.x * blockDim.x + threadIdx.x;
  if (e < E) atomicAdd(cnt + ei[E + e], 1);  // row 1 = dst
}

__global__ __launch_bounds__(1024) void k_scan(int* cntA, int* offsA, int* cntB, int* offsB, int N) {
  int* cnt  = blockIdx.x ? cntB  : cntA;   // counts in, cursor out (in place)
  int* offs = blockIdx.x ? offsB : offsA;
  __shared__ int wsum[16];
  __shared__ int s_carry, s_total;
  const int t = threadIdx.x, lane = t & 63, wid = t >> 6;
  if (t == 0) s_carry = 0;
  __syncthreads();
  for (int base = 0; base < N; base += 1024) {
    int i = base + t;
    int v = (i < N) ? cnt[i] : 0;
    int incl = v;
    #pragma unroll
    for (int d = 1; d < 64; d <<= 1) {
      int u = __shfl_up(incl, d, 64);
      if (lane >= d) incl += u;
    }
    if (lane == 63) wsum[wid] = incl;
    __syncthreads();
    if (wid == 0) {
      int ws = (lane < 16) ? wsum[lane] : 0;
      int wi = ws;
      #pragma unroll
      for (int d = 1; d < 16; d <<= 1) {
        int u = __shfl_up(wi, d, 64);
        if (lane >= d) wi += u;
      }
      if (lane < 16) wsum[lane] = wi - ws;  // exclusive wave prefix
      if (lane == 15) s_total = wi;
    }
    __syncthreads();
    int excl = s_carry + wsum[wid] + (incl - v);
    if (i < N) { offs[i] = excl; cnt[i] = excl; }
    __syncthreads();
    if (t == 0) s_carry += s_total;
    __syncthreads();
  }
  if (t == 0) offs[N] = s_carry;
}

__global__ void k_fill(const int* __restrict__ ei, const float* __restrict__ ew, int E,
                       int* __restrict__ cur, int* __restrict__ srcs, float* __restrict__ wts) {
  int e = blockIdx.x * blockDim.x + threadIdx.x;
  if (e < E) {
    int pos = atomicAdd(cur + ei[E + e], 1);
    srcs[pos] = ei[e];
    wts[pos]  = ew[e];
  }
}

// ---------------- weight prep ----------------
__global__ void k_wprep(const float* __restrict__ Wmi0, const float* __restrict__ Wmo0, const float* __restrict__ Ws0,
                        const float* __restrict__ Wmi1, const float* __restrict__ Wmo1, const float* __restrict__ Ws1,
                        const float* __restrict__ resW,
                        float* __restrict__ Wcat0, float* __restrict__ Wcat1) {
  int i = blockIdx.x * blockDim.x + threadIdx.x;
  if (i < 128 * 256) {
    int k = i >> 8, n = i & 255;
    float v = (n < 128) ? (Wmi0[k * 128 + n] + Ws0[k * 128 + n])
                        : (Wmo0[k * 128 + n - 128] + Ws0[k * 128 + n - 128]);
    Wcat0[i] = v;
  }
  if (i < 128 * 192) {
    int k = i / 192, n = i % 192;
    float v;
    if (n < 64)       v = Wmi1[k * 64 + n]       + Ws1[k * 64 + n];
    else if (n < 128) v = Wmo1[k * 64 + n - 64]  + Ws1[k * 64 + n - 64];
    else              v = resW[k * 64 + n - 128];
    Wcat1[k * 192 + n] = v;
  }
}

// ---------------- GEMM: C[N x DO] = A[N x 128] @ W[128 x DO], 64x64 tile, 4x4 per thread ----------------
// A-tile stored transposed in LDS (Ast[k][m], pad 65) so the a-fragment is one ds_read_b128
// (broadcast across 16 lanes) instead of 4 scalar ds_read_b32 -> kernel becomes VALU-bound.
__global__ __launch_bounds__(256) void k_gemm(const float* __restrict__ A,
                                              const float* __restrict__ W,
                                              float* __restrict__ C, int N, int DO) {
  __shared__ float Ast[64][65];  // [k][m]
  __shared__ float Bs[64][68];   // [k][n]
  const int t  = threadIdx.x;
  const int bm = blockIdx.x * 64;
  const int bn = blockIdx.y * 64;
  const int tx = t & 15, ty = t >> 4;
  const int sr = t >> 4;          // 0..15
  const int sc = (t & 15) * 4;    // 0..60
  float acc[4][4] = {};
  for (int kc = 0; kc < 128; kc += 64) {
    __syncthreads();
    #pragma unroll
    for (int j = 0; j < 4; ++j) {
      int r = j * 16 + sr;
      int gm = bm + r;
      float4 v = make_float4(0.f, 0.f, 0.f, 0.f);
      if (gm < N) v = *(const float4*)(A + (size_t)gm * 128 + kc + sc);
      Ast[sc + 0][r] = v.x; Ast[sc + 1][r] = v.y;
      Ast[sc + 2][r] = v.z; Ast[sc + 3][r] = v.w;
      *(float4*)(&Bs[r][sc]) = *(const float4*)(W + (size_t)(kc + r) * DO + bn + sc);
    }
    __syncthreads();
    #pragma unroll 8
    for (int k = 0; k < 64; ++k) {
      float4 a = *(const float4*)(&Ast[k][ty * 4]);
      float4 b = *(const float4*)(&Bs[k][tx * 4]);
      acc[0][0] = fmaf(a.x, b.x, acc[0][0]); acc[0][1] = fmaf(a.x, b.y, acc[0][1]);
      acc[0][2] = fmaf(a.x, b.z, acc[0][2]); acc[0][3] = fmaf(a.x, b.w, acc[0][3]);
      acc[1][0] = fmaf(a.y, b.x, acc[1][0]); acc[1][1] = fmaf(a.y, b.y, acc[1][1]);
      acc[1][2] = fmaf(a.y, b.z, acc[1][2]); acc[1][3] = fmaf(a.y, b.w, acc[1][3]);
      acc[2][0] = fmaf(a.z, b.x, acc[2][0]); acc[2][1] = fmaf(a.z, b.y, acc[2][1]);
      acc[2][2] = fmaf(a.z, b.z, acc[2][2]); acc[2][3] = fmaf(a.z, b.w, acc[2][3]);
      acc[3][0] = fmaf(a.w, b.x, acc[3][0]); acc[3][1] = fmaf(a.w, b.y, acc[3][1]);
      acc[3][2] = fmaf(a.w, b.z, acc[3][2]); acc[3][3] = fmaf(a.w, b.w, acc[3][3]);
    }
  }
  #pragma unroll
  for (int i = 0; i < 4; ++i) {
    int gm = bm + ty * 4 + i;
    if (gm < N) {
      float4 v = make_float4(acc[i][0], acc[i][1], acc[i][2], acc[i][3]);
      *(float4*)(C + (size_t)gm * DO + bn + tx * 4) = v;
    }
  }
}

// ---------------- pull aggregation, 128 cols (2 per lane), one wave per node ----------------
__global__ __launch_bounds__(256) void k_agg2(const float* __restrict__ T, int tstride, int coloff,
                                              const int* __restrict__ offs, const int* __restrict__ srcs,
                                              const float* __restrict__ wts,
                                              float* __restrict__ out, int ostride, int ooff, int N) {
  int n = (blockIdx.x * blockDim.x + threadIdx.x) >> 6;
  int lane = threadIdx.x & 63;
  if (n >= N) return;
  int s0 = offs[n], s1 = offs[n + 1];
  const float* base = T + coloff + lane * 2;
  float a0 = 0.f, a1 = 0.f;
  int i = s0;
  for (; i + 2 <= s1; i += 2) {
    int   sA = srcs[i], sB = srcs[i + 1];
    float wA = wts[i],  wB = wts[i + 1];
    float2 vA = *(const float2*)(base + (size_t)sA * tstride);
    float2 vB = *(const float2*)(base + (size_t)sB * tstride);
    a0 += wA * vA.x + wB * vB.x;
    a1 += wA * vA.y + wB * vB.y;
  }
  if (i < s1) {
    int sA = srcs[i]; float wA = wts[i];
    float2 vA = *(const float2*)(base + (size_t)sA * tstride);
    a0 += wA * vA.x; a1 += wA * vA.y;
  }
  *(float2*)(out + (size_t)n * ostride + ooff + lane * 2) = make_float2(a0, a1);
}

// ---------------- pull aggregation, 64 cols (1 per lane) ----------------
__global__ __launch_bounds__(256) void k_agg1(const float* __restrict__ T, int tstride, int coloff,
                                              const int* __restrict__ offs, const int* __restrict__ srcs,
                                              const float* __restrict__ wts,
                                              float* __restrict__ out, int ostride, int ooff, int N) {
  int n = (blockIdx.x * blockDim.x + threadIdx.x) >> 6;
  int lane = threadIdx.x & 63;
  if (n >= N) return;
  int s0 = offs[n], s1 = offs[n + 1];
  const float* base = T + coloff + lane;
  float a0 = 0.f;
  int i = s0;
  for (; i + 2 <= s1; i += 2) {
    int   sA = srcs[i], sB = srcs[i + 1];
    float wA = wts[i],  wB = wts[i + 1];
    a0 += wA * base[(size_t)sA * tstride] + wB * base[(size_t)sB * tstride];
  }
  if (i < s1) a0 += wts[i] * base[(size_t)srcs[i] * tstride];
  out[(size_t)n * ostride + ooff + lane] = a0;
}

// ---------------- h1 = tanh(cin*(aggin+bmi+bsi) + cout*(aggout+bmo+bso) + h0), in place ----------------
__global__ void k_h1(float* __restrict__ h, const float* __restrict__ agg,
                     const float* __restrict__ bmi, const float* __restrict__ bsi,
                     const float* __restrict__ bmo, const float* __restrict__ bso,
                     const float* __restrict__ cin, const float* __restrict__ cou, int N) {
  int i = blockIdx.x * blockDim.x + threadIdx.x;
  if (i >= N * 128) return;
  int n = i >> 7, f = i & 127;
  float ic = agg[(size_t)n * 256 + f]       + bmi[f] + bsi[f];
  float oc = agg[(size_t)n * 256 + 128 + f] + bmo[f] + bso[f];
  h[i] = tanhf(cin[n] * ic + cou[n] * oc + h[i]);
}

// ---------------- h2 = tanh(...) + fused L2-normalized emb output (64-lane shuffle reduce) ----------------
__global__ void k_h2(float* __restrict__ h2, float* __restrict__ emb,
                     const float* __restrict__ agg,
                     const float* __restrict__ tres,  // t1 + 128, row stride 192
                     const float* __restrict__ bmi, const float* __restrict__ bsi,
                     const float* __restrict__ bmo, const float* __restrict__ bso,
                     const float* __restrict__ resb,
                     const float* __restrict__ cin, const float* __restrict__ cou, int N) {
  int i = blockIdx.x * blockDim.x + threadIdx.x;
  if (i >= N * 64) return;
  int n = i >> 6, f = i & 63;
  float ic = agg[(size_t)n * 128 + f]      + bmi[f] + bsi[f];
  float oc = agg[(size_t)n * 128 + 64 + f] + bmo[f] + bso[f];
  float r  = tres[(size_t)n * 192 + f] + resb[f];
  float v = tanhf(cin[n] * ic + cou[n] * oc + r);
  h2[i] = v;
  float q = v * v;
  #pragma unroll
  for (int d = 32; d > 0; d >>= 1) q += __shfl_xor(q, d, 64);
  emb[(size_t)n * 64 + f] = v / (sqrtf(q) + 1e-12f);
}

// ---------------- decoder as register-tiled GEMM + fused log_softmax ----------------
// logits[N x 128] = h2[N x 64] @ Wd[64 x 128]; 64 nodes x 128 cols per block,
// per-thread 4x8 tile (cols tx*4 and 64+tx*4), K=64 single chunk.
__global__ __launch_bounds__(256) void k_dec(const float* __restrict__ h2,
                                             const float* __restrict__ Wd, const float* __restrict__ bd,
                                             float* __restrict__ logp, int N) {
  __shared__ float Ht[64][65];   // Ht[k][m] = h2[bm+m][k]
  __shared__ float Bs[64][132];  // Bs[k][c] = Wd[k][c]
  __shared__ float sb[128];
  const int t  = threadIdx.x;
  const int bm = blockIdx.x * 64;
  const int tx = t & 15, ty = t >> 4;
  const int sr = t >> 4;          // 0..15
  const int sc = (t & 15) * 4;    // 0..60
  #pragma unroll
  for (int j = 0; j < 4; ++j) {
    int r = j * 16 + sr;
    int gm = bm + r;
    float4 v = make_float4(0.f, 0.f, 0.f, 0.f);
    if (gm < N) v = *(const float4*)(h2 + (size_t)gm * 64 + sc);
    Ht[sc + 0][r] = v.x; Ht[sc + 1][r] = v.y;
    Ht[sc + 2][r] = v.z; Ht[sc + 3][r] = v.w;
    const float* wrow = Wd + (size_t)r * 128 + tx * 8;
    *(float4*)(&Bs[r][tx * 8])     = *(const float4*)(wrow);
    *(float4*)(&Bs[r][tx * 8 + 4]) = *(const float4*)(wrow + 4);
  }
  if (t < 128) sb[t] = bd[t];
  __syncthreads();
  float acc[4][8] = {};
  #pragma unroll 8
  for (int k = 0; k < 64; ++k) {
    float4 a  = *(const float4*)(&Ht[k][ty * 4]);
    float4 b0 = *(const float4*)(&Bs[k][tx * 4]);
    float4 b1 = *(const float4*)(&Bs[k][64 + tx * 4]);
    acc[0][0] = fmaf(a.x, b0.x, acc[0][0]); acc[0][1] = fmaf(a.x, b0.y, acc[0][1]);
    acc[0][2] = fmaf(a.x, b0.z, acc[0][2]); acc[0][3] = fmaf(a.x, b0.w, acc[0][3]);
    acc[0][4] = fmaf(a.x, b1.x, acc[0][4]); acc[0][5] = fmaf(a.x, b1.y, acc[0][5]);
    acc[0][6] = fmaf(a.x, b1.z, acc[0][6]); acc[0][7] = fmaf(a.x, b1.w, acc[0][7]);
    acc[1][0] = fmaf(a.y, b0.x, acc[1][0]); acc[1][1] = fmaf(a.y, b0.y, acc[1][1]);
    acc[1][2] = fmaf(a.y, b0.z, acc[1][2]); acc[1][3] = fmaf(a.y, b0.w, acc[1][3]);
    acc[1][4] = fmaf(a.y, b1.x, acc[1][4]); acc[1][5] = fmaf(a.y, b1.y, acc[1][5]);
    acc[1][6] = fmaf(a.y, b1.z, acc[1][6]); acc[1][7] = fmaf(a.y, b1.w, acc[1][7]);
    acc[2][0] = fmaf(a.z, b0.x, acc[2][0]); acc[2][1] = fmaf(a.z, b0.y, acc[2][1]);
    acc[2][2] = fmaf(a.z, b0.z, acc[2][2]); acc[2][3] = fmaf(a.z, b0.w, acc[2][3]);
    acc[2][4] = fmaf(a.z, b1.x, acc[2][4]); acc[2][5] = fmaf(a.z, b1.y, acc[2][5]);
    acc[2][6] = fmaf(a.z, b1.z, acc[2][6]); acc[2][7] = fmaf(a.z, b1.w, acc[2][7]);
    acc[3][0] = fmaf(a.w, b0.x, acc[3][0]); acc[3][1] = fmaf(a.w, b0.y, acc[3][1]);
    acc[3][2] = fmaf(a.w, b0.z, acc[3][2]); acc[3][3] = fmaf(a.w, b0.w, acc[3][3]);
    acc[3][4] = fmaf(a.w, b1.x, acc[3][4]); acc[3][5] = fmaf(a.w, b1.y, acc[3][5]);
    acc[3][6] = fmaf(a.w, b1.z, acc[3][6]); acc[3][7] = fmaf(a.w, b1.w, acc[3][7]);
  }
  float bb[8];
  #pragma unroll
  for (int j = 0; j < 4; ++j) { bb[j] = sb[tx * 4 + j]; bb[4 + j] = sb[64 + tx * 4 + j]; }
  #pragma unroll
  for (int i = 0; i < 4; ++i) {
    int gm = bm + ty * 4 + i;
    float v[8];
    #pragma unroll
    for (int j = 0; j < 8; ++j) v[j] = acc[i][j] + bb[j];
    float m = v[0];
    #pragma unroll
    for (int j = 1; j < 8; ++j) m = fmaxf(m, v[j]);
    #pragma unroll
    for (int d = 1; d < 16; d <<= 1) m = fmaxf(m, __shfl_xor(m, d, 64));
    float s = 0.f;
    #pragma unroll
    for (int j = 0; j < 8; ++j) s += __expf(v[j] - m);
    #pragma unroll
    for (int d = 1; d < 16; d <<= 1) s += __shfl_xor(s, d, 64);
    float lse = m + __logf(s);
    if (gm < N) {
      float4 o0 = make_float4(v[0] - lse, v[1] - lse, v[2] - lse, v[3] - lse);
      float4 o1 = make_float4(v[4] - lse, v[5] - lse, v[6] - lse, v[7] - lse);
      *(float4*)(logp + (size_t)gm * 128 + tx * 4)      = o0;
      *(float4*)(logp + (size_t)gm * 128 + 64 + tx * 4) = o1;
    }
  }
}

extern "C" void kernel_launch(void* const* d_in, const int* in_sizes, int n_in,
                              void* d_out, int out_size, void* d_ws, size_t ws_size,
                              hipStream_t stream) {
  const float* x     = (const float*)d_in[0];
  const int*   ei_in = (const int*)d_in[1];
  const float* ew_in = (const float*)d_in[2];
  const int*   ei_ou = (const int*)d_in[3];
  const float* ew_ou = (const float*)d_in[4];
  const float* pe    = (const float*)d_in[5];
  const float* Wmi0  = (const float*)d_in[6];
  const float* Wmo0  = (const float*)d_in[7];
  const float* Wsh0  = (const float*)d_in[8];
  const float* bmi0  = (const float*)d_in[9];
  const float* bmo0  = (const float*)d_in[10];
  const float* bsi0  = (const float*)d_in[11];
  const float* bso0  = (const float*)d_in[12];
  const float* cin0  = (const float*)d_in[13];
  const float* cou0  = (const float*)d_in[14];
  const float* Wmi1  = (const float*)d_in[15];
  const float* Wmo1  = (const float*)d_in[16];
  const float* Wsh1  = (const float*)d_in[17];
  const float* bmi1  = (const float*)d_in[18];
  const float* bmo1  = (const float*)d_in[19];
  const float* bsi1  = (const float*)d_in[20];
  const float* bso1  = (const float*)d_in[21];
  const float* cin1  = (const float*)d_in[22];
  const float* cou1  = (const float*)d_in[23];
  const float* resW  = (const float*)d_in[24];
  const float* resb  = (const float*)d_in[25];
  const float* Wd    = (const float*)d_in[26];
  const float* bd    = (const float*)d_in[27];

  const int N = in_sizes[0] / 128;
  const int E = in_sizes[2];

  char* ws = (char*)d_ws;
  size_t off = 0;
  auto alloc = [&](size_t bytes) -> char* {
    off = (off + 255) & ~(size_t)255;
    char* p = ws + off;
    off += bytes;
    return p;
  };
  float* hbuf   = (float*)alloc((size_t)N * 128 * 4);  // h0 -> h1 (in place) -> h2 (overlay)
  float* tbuf   = (float*)alloc((size_t)N * 256 * 4);  // t0 (N x 256) -> t1 (N x 192)
  float* aggbuf = (float*)alloc((size_t)N * 256 * 4);  // agg0 (N x 256) -> agg1 (N x 128)
  float* Wcat0  = (float*)alloc(128 * 256 * 4);
  float* Wcat1  = (float*)alloc(128 * 192 * 4);
  int*   offsI  = (int*)alloc((size_t)(N + 1) * 4);
  int*   curI   = (int*)alloc((size_t)N * 4);
  int*   srcsI  = (int*)alloc((size_t)E * 4);
  float* wtsI   = (float*)alloc((size_t)E * 4);
  int*   offsO  = (int*)alloc((size_t)(N + 1) * 4);
  int*   curO   = (int*)alloc((size_t)N * 4);
  int*   srcsO  = (int*)alloc((size_t)E * 4);
  float* wtsO   = (float*)alloc((size_t)E * 4);
  float* h2buf  = hbuf;  // overlay: h1 dead after gemm1 (residual carried inside t1)

  (void)hipMemsetAsync(curI, 0, (size_t)N * 4, stream);
  (void)hipMemsetAsync(curO, 0, (size_t)N * 4, stream);

  const int eb = (E + 255) / 256;
  k_pe<<<(N * 128 + 255) / 256, 256, 0, stream>>>(x, pe, hbuf, N * 128);
  k_hist<<<eb, 256, 0, stream>>>(ei_in, E, curI);
  k_hist<<<eb, 256, 0, stream>>>(ei_ou, E, curO);
  k_scan<<<2, 1024, 0, stream>>>(curI, offsI, curO, offsO, N);
  k_fill<<<eb, 256, 0, stream>>>(ei_in, ew_in, E, curI, srcsI, wtsI);
  k_fill<<<eb, 256, 0, stream>>>(ei_ou, ew_ou, E, curO, srcsO, wtsO);
  k_wprep<<<(128 * 256 + 255) / 256, 256, 0, stream>>>(Wmi0, Wmo0, Wsh0, Wmi1, Wmo1, Wsh1, resW, Wcat0, Wcat1);

  dim3 g0((N + 63) / 64, 4);
  k_gemm<<<g0, 256, 0, stream>>>(hbuf, Wcat0, tbuf, N, 256);
  int ab = (N + 3) / 4;
  k_agg2<<<ab, 256, 0, stream>>>(tbuf, 256, 0,   offsI, srcsI, wtsI, aggbuf, 256, 0,   N);
  k_agg2<<<ab, 256, 0, stream>>>(tbuf, 256, 128, offsO, srcsO, wtsO, aggbuf, 256, 128, N);
  k_h1<<<(N * 128 + 255) / 256, 256, 0, stream>>>(hbuf, aggbuf, bmi0, bsi0, bmo0, bso0, cin0, cou0, N);

  dim3 g1((N + 63) / 64, 3);
  k_gemm<<<g1, 256, 0, stream>>>(hbuf, Wcat1, tbuf, N, 192);
  k_agg1<<<ab, 256, 0, stream>>>(tbuf, 192, 0,  offsI, srcsI, wtsI, aggbuf, 128, 0,  N);
  k_agg1<<<ab, 256, 0, stream>>>(tbuf, 192, 64, offsO, srcsO, wtsO, aggbuf, 128, 64, N);

  float* logp = (float*)d_out;
  float* emb  = logp + (size_t)N * 128;
  k_h2<<<(N * 64 + 255) / 256, 256, 0, stream>>>(h2buf, emb, aggbuf, tbuf + 128,
                                                 bmi1, bsi1, bmo1, bso1, resb, cin1, cou1, N);
  k_dec<<<(N + 63) / 64, 256, 0, stream>>>(h2buf, Wd, bd, logp, N);
}

// Round 3
// 613.299 us; speedup vs baseline: 1.2723x; 1.2144x over previous
//
#include <hip/hip_runtime.h>
#include <hip/hip_bf16.h>
#include <math.h>

typedef __hip_bfloat16  bf16;
typedef __hip_bfloat162 bf162;

// ---------------- CSR build: histogram both edge sets (blockIdx.y selects) ----------------
__global__ void k_hist(const int* __restrict__ eiIn, const int* __restrict__ eiOut,
                       int E, int* __restrict__ cur, int N) {
  int e = blockIdx.x * blockDim.x + threadIdx.x;
  if (e >= E) return;
  const int* ei = blockIdx.y ? eiOut : eiIn;
  atomicAdd(cur + blockIdx.y * N + ei[E + e], 1);
}

__global__ __launch_bounds__(1024) void k_scan(int* cur, int* offsI, int* offsO, int N) {
  int* cnt  = cur + blockIdx.x * N;         // counts in, cursor out (in place)
  int* offs = blockIdx.x ? offsO : offsI;
  __shared__ int wsum[16];
  __shared__ int s_carry, s_total;
  const int t = threadIdx.x, lane = t & 63, wid = t >> 6;
  if (t == 0) s_carry = 0;
  __syncthreads();
  for (int base = 0; base < N; base += 1024) {
    int i = base + t;
    int v = (i < N) ? cnt[i] : 0;
    int incl = v;
    #pragma unroll
    for (int d = 1; d < 64; d <<= 1) {
      int u = __shfl_up(incl, d, 64);
      if (lane >= d) incl += u;
    }
    if (lane == 63) wsum[wid] = incl;
    __syncthreads();
    if (wid == 0) {
      int ws = (lane < 16) ? wsum[lane] : 0;
      int wi = ws;
      #pragma unroll
      for (int d = 1; d < 16; d <<= 1) {
        int u = __shfl_up(wi, d, 64);
        if (lane >= d) wi += u;
      }
      if (lane < 16) wsum[lane] = wi - ws;  // exclusive wave prefix
      if (lane == 15) s_total = wi;
    }
    __syncthreads();
    int excl = s_carry + wsum[wid] + (incl - v);
    if (i < N) { offs[i] = excl; cnt[i] = excl; }
    __syncthreads();
    if (t == 0) s_carry += s_total;
    __syncthreads();
  }
  if (t == 0) offs[N] = s_carry;
}

__global__ void k_fill(const int* __restrict__ eiIn, const float* __restrict__ ewIn,
                       const int* __restrict__ eiOut, const float* __restrict__ ewOut,
                       int E, int* __restrict__ cur,
                       int2* __restrict__ eI, int2* __restrict__ eO, int N) {
  int e = blockIdx.x * blockDim.x + threadIdx.x;
  if (e >= E) return;
  int y = blockIdx.y;
  const int*   ei = y ? eiOut : eiIn;
  const float* ew = y ? ewOut : ewIn;
  int2* dst = y ? eO : eI;
  int pos = atomicAdd(cur + y * N + ei[E + e], 1);
  dst[pos] = make_int2(ei[e], __float_as_int(ew[e]));
}

// ---------------- weight prep: concat weights + pre-combined biases ----------------
__global__ void k_wprep(const float* __restrict__ Wmi0, const float* __restrict__ Wmo0, const float* __restrict__ Ws0,
                        const float* __restrict__ Wmi1, const float* __restrict__ Wmo1, const float* __restrict__ Ws1,
                        const float* __restrict__ resW,
                        const float* __restrict__ bmi0, const float* __restrict__ bsi0,
                        const float* __restrict__ bmo0, const float* __restrict__ bso0,
                        const float* __restrict__ bmi1, const float* __restrict__ bsi1,
                        const float* __restrict__ bmo1, const float* __restrict__ bso1,
                        float* __restrict__ Wcat0, float* __restrict__ Wcat1,
                        float* __restrict__ bi0, float* __restrict__ bo0,
                        float* __restrict__ bi1, float* __restrict__ bo1) {
  int i = blockIdx.x * blockDim.x + threadIdx.x;
  if (i < 128 * 256) {
    int k = i >> 8, n = i & 255;
    float v = (n < 128) ? (Wmi0[k * 128 + n] + Ws0[k * 128 + n])
                        : (Wmo0[k * 128 + n - 128] + Ws0[k * 128 + n - 128]);
    Wcat0[i] = v;
  }
  if (i < 128 * 192) {
    int k = i / 192, n = i % 192;
    float v;
    if (n < 64)       v = Wmi1[k * 64 + n]       + Ws1[k * 64 + n];
    else if (n < 128) v = Wmo1[k * 64 + n - 64]  + Ws1[k * 64 + n - 64];
    else              v = resW[k * 64 + n - 128];
    Wcat1[k * 192 + n] = v;
  }
  if (i < 128) { bi0[i] = bmi0[i] + bsi0[i]; bo0[i] = bmo0[i] + bso0[i]; }
  if (i < 64)  { bi1[i] = bmi1[i] + bsi1[i]; bo1[i] = bmo1[i] + bso1[i]; }
}

// ---------------- GEMM: C_bf16[N x DO] = (A[N x 128] (+pe)) @ W[128 x DO], 64x64 tile ----------------
__global__ __launch_bounds__(256) void k_gemm(const float* __restrict__ A,
                                              const float* __restrict__ pe,  // nullptr if none
                                              const float* __restrict__ W,
                                              bf16* __restrict__ C, int N, int DO) {
  __shared__ float Ast[64][65];  // [k][m] transposed
  __shared__ float Bs[64][68];   // [k][n]
  const int t  = threadIdx.x;
  const int bm = blockIdx.x * 64;
  const int bn = blockIdx.y * 64;
  const int tx = t & 15, ty = t >> 4;
  const int sr = t >> 4;
  const int sc = (t & 15) * 4;
  float acc[4][4] = {};
  for (int kc = 0; kc < 128; kc += 64) {
    __syncthreads();
    #pragma unroll
    for (int j = 0; j < 4; ++j) {
      int r = j * 16 + sr;
      int gm = bm + r;
      float4 v = make_float4(0.f, 0.f, 0.f, 0.f);
      if (gm < N) {
        v = *(const float4*)(A + (size_t)gm * 128 + kc + sc);
        if (pe) {
          float4 p = *(const float4*)(pe + kc + sc);
          v.x += p.x; v.y += p.y; v.z += p.z; v.w += p.w;
        }
      }
      Ast[sc + 0][r] = v.x; Ast[sc + 1][r] = v.y;
      Ast[sc + 2][r] = v.z; Ast[sc + 3][r] = v.w;
      *(float4*)(&Bs[r][sc]) = *(const float4*)(W + (size_t)(kc + r) * DO + bn + sc);
    }
    __syncthreads();
    #pragma unroll 8
    for (int k = 0; k < 64; ++k) {
      float4 a = *(const float4*)(&Ast[k][ty * 4]);
      float4 b = *(const float4*)(&Bs[k][tx * 4]);
      acc[0][0] = fmaf(a.x, b.x, acc[0][0]); acc[0][1] = fmaf(a.x, b.y, acc[0][1]);
      acc[0][2] = fmaf(a.x, b.z, acc[0][2]); acc[0][3] = fmaf(a.x, b.w, acc[0][3]);
      acc[1][0] = fmaf(a.y, b.x, acc[1][0]); acc[1][1] = fmaf(a.y, b.y, acc[1][1]);
      acc[1][2] = fmaf(a.y, b.z, acc[1][2]); acc[1][3] = fmaf(a.y, b.w, acc[1][3]);
      acc[2][0] = fmaf(a.z, b.x, acc[2][0]); acc[2][1] = fmaf(a.z, b.y, acc[2][1]);
      acc[2][2] = fmaf(a.z, b.z, acc[2][2]); acc[2][3] = fmaf(a.z, b.w, acc[2][3]);
      acc[3][0] = fmaf(a.w, b.x, acc[3][0]); acc[3][1] = fmaf(a.w, b.y, acc[3][1]);
      acc[3][2] = fmaf(a.w, b.z, acc[3][2]); acc[3][3] = fmaf(a.w, b.w, acc[3][3]);
    }
  }
  #pragma unroll
  for (int i = 0; i < 4; ++i) {
    int gm = bm + ty * 4 + i;
    if (gm < N) {
      bf162* cp = (bf162*)(C + (size_t)gm * DO + bn + tx * 4);
      cp[0] = __float22bfloat162_rn(make_float2(acc[i][0], acc[i][1]));
      cp[1] = __float22bfloat162_rn(make_float2(acc[i][2], acc[i][3]));
    }
  }
}

// ---------------- layer 0: in-gather + out-gather + epilogue -> h1 (one wave per node) ----------------
// tbuf rows: 256 bf16 (cols 0-127 in-transform, 128-255 out-transform). Lane owns cols lane*2, lane*2+1.
__global__ __launch_bounds__(256) void k_aggL0(const bf16* __restrict__ tb,
                                               const int* __restrict__ offsI, const int2* __restrict__ eI,
                                               const int* __restrict__ offsO, const int2* __restrict__ eO,
                                               const float* __restrict__ bi, const float* __restrict__ bo,
                                               const float* __restrict__ cin, const float* __restrict__ cou,
                                               const float* __restrict__ x, const float* __restrict__ pe,
                                               float* __restrict__ h1, int N) {
  int n = (blockIdx.x * blockDim.x + threadIdx.x) >> 6;
  int lane = threadIdx.x & 63;
  if (n >= N) return;
  const int c = lane * 2;
  float a0 = 0.f, a1 = 0.f, b0 = 0.f, b1 = 0.f;
  {
    int s0 = offsI[n], s1 = offsI[n + 1];
    int i = s0;
    for (; i + 3 < s1; i += 4) {
      int2 eA = eI[i], eB = eI[i + 1], eC = eI[i + 2], eD = eI[i + 3];
      float2 vA = __bfloat1622float2(*(const bf162*)(tb + (size_t)eA.x * 256 + c));
      float2 vB = __bfloat1622float2(*(const bf162*)(tb + (size_t)eB.x * 256 + c));
      float2 vC = __bfloat1622float2(*(const bf162*)(tb + (size_t)eC.x * 256 + c));
      float2 vD = __bfloat1622float2(*(const bf162*)(tb + (size_t)eD.x * 256 + c));
      float wA = __int_as_float(eA.y), wB = __int_as_float(eB.y);
      float wC = __int_as_float(eC.y), wD = __int_as_float(eD.y);
      a0 += wA * vA.x + wB * vB.x + wC * vC.x + wD * vD.x;
      a1 += wA * vA.y + wB * vB.y + wC * vC.y + wD * vD.y;
    }
    for (; i < s1; ++i) {
      int2 e = eI[i];
      float2 v = __bfloat1622float2(*(const bf162*)(tb + (size_t)e.x * 256 + c));
      float w = __int_as_float(e.y);
      a0 += w * v.x; a1 += w * v.y;
    }
  }
  {
    int s0 = offsO[n], s1 = offsO[n + 1];
    int i = s0;
    for (; i + 3 < s1; i += 4) {
      int2 eA = eO[i], eB = eO[i + 1], eC = eO[i + 2], eD = eO[i + 3];
      float2 vA = __bfloat1622float2(*(const bf162*)(tb + (size_t)eA.x * 256 + 128 + c));
      float2 vB = __bfloat1622float2(*(const bf162*)(tb + (size_t)eB.x * 256 + 128 + c));
      float2 vC = __bfloat1622float2(*(const bf162*)(tb + (size_t)eC.x * 256 + 128 + c));
      float2 vD = __bfloat1622float2(*(const bf162*)(tb + (size_t)eD.x * 256 + 128 + c));
      float wA = __int_as_float(eA.y), wB = __int_as_float(eB.y);
      float wC = __int_as_float(eC.y), wD = __int_as_float(eD.y);
      b0 += wA * vA.x + wB * vB.x + wC * vC.x + wD * vD.x;
      b1 += wA * vA.y + wB * vB.y + wC * vC.y + wD * vD.y;
    }
    for (; i < s1; ++i) {
      int2 e = eO[i];
      float2 v = __bfloat1622float2(*(const bf162*)(tb + (size_t)e.x * 256 + 128 + c));
      float w = __int_as_float(e.y);
      b0 += w * v.x; b1 += w * v.y;
    }
  }
  float ci = cin[n], co = cou[n];
  float2 bif = *(const float2*)(bi + c);
  float2 bof = *(const float2*)(bo + c);
  float2 x2  = *(const float2*)(x + (size_t)n * 128 + c);
  float2 p2  = *(const float2*)(pe + c);
  float v0 = tanhf(ci * (a0 + bif.x) + co * (b0 + bof.x) + x2.x + p2.x);
  float v1 = tanhf(ci * (a1 + bif.y) + co * (b1 + bof.y) + x2.y + p2.y);
  *(float2*)(h1 + (size_t)n * 128 + c) = make_float2(v0, v1);
}

// ---------------- layer 1: in/out gather (half-wave per edge) + epilogue -> h2, emb ----------------
// t1 rows: 192 bf16 (0-63 in, 64-127 out, 128-191 residual). Half-wave (32 lanes) covers one edge row.
__global__ __launch_bounds__(256) void k_aggL1(const bf16* __restrict__ t1,
                                               const int* __restrict__ offsI, const int2* __restrict__ eI,
                                               const int* __restrict__ offsO, const int2* __restrict__ eO,
                                               const float* __restrict__ bi, const float* __restrict__ bo,
                                               const float* __restrict__ resb,
                                               const float* __restrict__ cin, const float* __restrict__ cou,
                                               float* __restrict__ h2, float* __restrict__ emb, int N) {
  int n = (blockIdx.x * blockDim.x + threadIdx.x) >> 6;
  int lane = threadIdx.x & 63;
  if (n >= N) return;
  const int sub = lane >> 5;        // which half-wave
  const int sl  = lane & 31;        // position within half
  const int c = sl * 2;             // 2 cols per lane within 64-col group
  float a0 = 0.f, a1 = 0.f, b0 = 0.f, b1 = 0.f;
  {
    int s0 = offsI[n], s1 = offsI[n + 1];
    int i = s0 + sub;
    for (; i + 6 < s1; i += 8) {
      int2 eA = eI[i], eB = eI[i + 2], eC = eI[i + 4], eD = eI[i + 6];
      float2 vA = __bfloat1622float2(*(const bf162*)(t1 + (size_t)eA.x * 192 + c));
      float2 vB = __bfloat1622float2(*(const bf162*)(t1 + (size_t)eB.x * 192 + c));
      float2 vC = __bfloat1622float2(*(const bf162*)(t1 + (size_t)eC.x * 192 + c));
      float2 vD = __bfloat1622float2(*(const bf162*)(t1 + (size_t)eD.x * 192 + c));
      float wA = __int_as_float(eA.y), wB = __int_as_float(eB.y);
      float wC = __int_as_float(eC.y), wD = __int_as_float(eD.y);
      a0 += wA * vA.x + wB * vB.x + wC * vC.x + wD * vD.x;
      a1 += wA * vA.y + wB * vB.y + wC * vC.y + wD * vD.y;
    }
    for (; i < s1; i += 2) {
      int2 e = eI[i];
      float2 v = __bfloat1622float2(*(const bf162*)(t1 + (size_t)e.x * 192 + c));
      float w = __int_as_float(e.y);
      a0 += w * v.x; a1 += w * v.y;
    }
  }
  {
    int s0 = offsO[n], s1 = offsO[n + 1];
    int i = s0 + sub;
    for (; i + 6 < s1; i += 8) {
      int2 eA = eO[i], eB = eO[i + 2], eC = eO[i + 4], eD = eO[i + 6];
      float2 vA = __bfloat1622float2(*(const bf162*)(t1 + (size_t)eA.x * 192 + 64 + c));
      float2 vB = __bfloat1622float2(*(const bf162*)(t1 + (size_t)eB.x * 192 + 64 + c));
      float2 vC = __bfloat1622float2(*(const bf162*)(t1 + (size_t)eC.x * 192 + 64 + c));
      float2 vD = __bfloat1622float2(*(const bf162*)(t1 + (size_t)eD.x * 192 + 64 + c));
      float wA = __int_as_float(eA.y), wB = __int_as_float(eB.y);
      float wC = __int_as_float(eC.y), wD = __int_as_float(eD.y);
      b0 += wA * vA.x + wB * vB.x + wC * vC.x + wD * vD.x;
      b1 += wA * vA.y + wB * vB.y + wC * vC.y + wD * vD.y;
    }
    for (; i < s1; i += 2) {
      int2 e = eO[i];
      float2 v = __bfloat1622float2(*(const bf162*)(t1 + (size_t)e.x * 192 + 64 + c));
      float w = __int_as_float(e.y);
      b0 += w * v.x; b1 += w * v.y;
    }
  }
  // combine the two half-wave partials
  a0 += __shfl_xor(a0, 32, 64); a1 += __shfl_xor(a1, 32, 64);
  b0 += __shfl_xor(b0, 32, 64); b1 += __shfl_xor(b1, 32, 64);
  float ci = cin[n], co = cou[n];
  float2 bif = *(const float2*)(bi + c);
  float2 bof = *(const float2*)(bo + c);
  float2 rb  = *(const float2*)(resb + c);
  float2 rv  = __bfloat1622float2(*(const bf162*)(t1 + (size_t)n * 192 + 128 + c));
  float v0 = tanhf(ci * (a0 + bif.x) + co * (b0 + bof.x) + rv.x + rb.x);
  float v1 = tanhf(ci * (a1 + bif.y) + co * (b1 + bof.y) + rv.y + rb.y);
  float q = v0 * v0 + v1 * v1;
  #pragma unroll
  for (int d = 16; d > 0; d >>= 1) q += __shfl_xor(q, d, 64);  // reduce within each 32-half (covers all 64 cols)
  float inv = 1.0f / (sqrtf(q) + 1e-12f);
  if (sub == 0) {
    *(float2*)(h2  + (size_t)n * 64 + c) = make_float2(v0, v1);
    *(float2*)(emb + (size_t)n * 64 + c) = make_float2(v0 * inv, v1 * inv);
  }
}

// ---------------- decoder as register-tiled GEMM + fused log_softmax ----------------
__global__ __launch_bounds__(256) void k_dec(const float* __restrict__ h2,
                                             const float* __restrict__ Wd, const float* __restrict__ bd,
                                             float* __restrict__ logp, int N) {
  __shared__ float Ht[64][65];   // Ht[k][m] = h2[bm+m][k]
  __shared__ float Bs[64][132];  // Bs[k][c] = Wd[k][c]
  __shared__ float sb[128];
  const int t  = threadIdx.x;
  const int bm = blockIdx.x * 64;
  const int tx = t & 15, ty = t >> 4;
  const int sr = t >> 4;
  const int sc = (t & 15) * 4;
  #pragma unroll
  for (int j = 0; j < 4; ++j) {
    int r = j * 16 + sr;
    int gm = bm + r;
    float4 v = make_float4(0.f, 0.f, 0.f, 0.f);
    if (gm < N) v = *(const float4*)(h2 + (size_t)gm * 64 + sc);
    Ht[sc + 0][r] = v.x; Ht[sc + 1][r] = v.y;
    Ht[sc + 2][r] = v.z; Ht[sc + 3][r] = v.w;
    const float* wrow = Wd + (size_t)r * 128 + tx * 8;
    *(float4*)(&Bs[r][tx * 8])     = *(const float4*)(wrow);
    *(float4*)(&Bs[r][tx * 8 + 4]) = *(const float4*)(wrow + 4);
  }
  if (t < 128) sb[t] = bd[t];
  __syncthreads();
  float acc[4][8] = {};
  #pragma unroll 8
  for (int k = 0; k < 64; ++k) {
    float4 a  = *(const float4*)(&Ht[k][ty * 4]);
    float4 b0 = *(const float4*)(&Bs[k][tx * 4]);
    float4 b1 = *(const float4*)(&Bs[k][64 + tx * 4]);
    acc[0][0] = fmaf(a.x, b0.x, acc[0][0]); acc[0][1] = fmaf(a.x, b0.y, acc[0][1]);
    acc[0][2] = fmaf(a.x, b0.z, acc[0][2]); acc[0][3] = fmaf(a.x, b0.w, acc[0][3]);
    acc[0][4] = fmaf(a.x, b1.x, acc[0][4]); acc[0][5] = fmaf(a.x, b1.y, acc[0][5]);
    acc[0][6] = fmaf(a.x, b1.z, acc[0][6]); acc[0][7] = fmaf(a.x, b1.w, acc[0][7]);
    acc[1][0] = fmaf(a.y, b0.x, acc[1][0]); acc[1][1] = fmaf(a.y, b0.y, acc[1][1]);
    acc[1][2] = fmaf(a.y, b0.z, acc[1][2]); acc[1][3] = fmaf(a.y, b0.w, acc[1][3]);
    acc[1][4] = fmaf(a.y, b1.x, acc[1][4]); acc[1][5] = fmaf(a.y, b1.y, acc[1][5]);
    acc[1][6] = fmaf(a.y, b1.z, acc[1][6]); acc[1][7] = fmaf(a.y, b1.w, acc[1][7]);
    acc[2][0] = fmaf(a.z, b0.x, acc[2][0]); acc[2][1] = fmaf(a.z, b0.y, acc[2][1]);
    acc[2][2] = fmaf(a.z, b0.z, acc[2][2]); acc[2][3] = fmaf(a.z, b0.w, acc[2][3]);
    acc[2][4] = fmaf(a.z, b1.x, acc[2][4]); acc[2][5] = fmaf(a.z, b1.y, acc[2][5]);
    acc[2][6] = fmaf(a.z, b1.z, acc[2][6]); acc[2][7] = fmaf(a.z, b1.w, acc[2][7]);
    acc[3][0] = fmaf(a.w, b0.x, acc[3][0]); acc[3][1] = fmaf(a.w, b0.y, acc[3][1]);
    acc[3][2] = fmaf(a.w, b0.z, acc[3][2]); acc[3][3] = fmaf(a.w, b0.w, acc[3][3]);
    acc[3][4] = fmaf(a.w, b1.x, acc[3][4]); acc[3][5] = fmaf(a.w, b1.y, acc[3][5]);
    acc[3][6] = fmaf(a.w, b1.z, acc[3][6]); acc[3][7] = fmaf(a.w, b1.w, acc[3][7]);
  }
  float bb[8];
  #pragma unroll
  for (int j = 0; j < 4; ++j) { bb[j] = sb[tx * 4 + j]; bb[4 + j] = sb[64 + tx * 4 + j]; }
  #pragma unroll
  for (int i = 0; i < 4; ++i) {
    int gm = bm + ty * 4 + i;
    float v[8];
    #pragma unroll
    for (int j = 0; j < 8; ++j) v[j] = acc[i][j] + bb[j];
    float m = v[0];
    #pragma unroll
    for (int j = 1; j < 8; ++j) m = fmaxf(m, v[j]);
    #pragma unroll
    for (int d = 1; d < 16; d <<= 1) m = fmaxf(m, __shfl_xor(m, d, 64));
    float s = 0.f;
    #pragma unroll
    for (int j = 0; j < 8; ++j) s += __expf(v[j] - m);
    #pragma unroll
    for (int d = 1; d < 16; d <<= 1) s += __shfl_xor(s, d, 64);
    float lse = m + __logf(s);
    if (gm < N) {
      float4 o0 = make_float4(v[0] - lse, v[1] - lse, v[2] - lse, v[3] - lse);
      float4 o1 = make_float4(v[4] - lse, v[5] - lse, v[6] - lse, v[7] - lse);
      *(float4*)(logp + (size_t)gm * 128 + tx * 4)      = o0;
      *(float4*)(logp + (size_t)gm * 128 + 64 + tx * 4) = o1;
    }
  }
}

extern "C" void kernel_launch(void* const* d_in, const int* in_sizes, int n_in,
                              void* d_out, int out_size, void* d_ws, size_t ws_size,
                              hipStream_t stream) {
  const float* x     = (const float*)d_in[0];
  const int*   ei_in = (const int*)d_in[1];
  const float* ew_in = (const float*)d_in[2];
  const int*   ei_ou = (const int*)d_in[3];
  const float* ew_ou = (const float*)d_in[4];
  const float* pe    = (const float*)d_in[5];
  const float* Wmi0  = (const float*)d_in[6];
  const float* Wmo0  = (const float*)d_in[7];
  const float* Wsh0  = (const float*)d_in[8];
  const float* bmi0  = (const float*)d_in[9];
  const float* bmo0  = (const float*)d_in[10];
  const float* bsi0  = (const float*)d_in[11];
  const float* bso0  = (const float*)d_in[12];
  const float* cin0  = (const float*)d_in[13];
  const float* cou0  = (const float*)d_in[14];
  const float* Wmi1  = (const float*)d_in[15];
  const float* Wmo1  = (const float*)d_in[16];
  const float* Wsh1  = (const float*)d_in[17];
  const float* bmi1  = (const float*)d_in[18];
  const float* bmo1  = (const float*)d_in[19];
  const float* bsi1  = (const float*)d_in[20];
  const float* bso1  = (const float*)d_in[21];
  const float* cin1  = (const float*)d_in[22];
  const float* cou1  = (const float*)d_in[23];
  const float* resW  = (const float*)d_in[24];
  const float* resb  = (const float*)d_in[25];
  const float* Wd    = (const float*)d_in[26];
  const float* bd    = (const float*)d_in[27];

  const int N = in_sizes[0] / 128;
  const int E = in_sizes[2];

  char* ws = (char*)d_ws;
  size_t off = 0;
  auto alloc = [&](size_t bytes) -> char* {
    off = (off + 255) & ~(size_t)255;
    char* p = ws + off;
    off += bytes;
    return p;
  };
  bf16*  tbuf  = (bf16*)alloc((size_t)N * 256 * 2);   // t0 (N x 256 bf16) -> t1 (N x 192 bf16)
  float* hbuf  = (float*)alloc((size_t)N * 128 * 4);  // h1 -> h2 (overlay, N x 64)
  float* Wcat0 = (float*)alloc(128 * 256 * 4);
  float* Wcat1 = (float*)alloc(128 * 192 * 4);
  float* bi0   = (float*)alloc(128 * 4);
  float* bo0   = (float*)alloc(128 * 4);
  float* bi1   = (float*)alloc(64 * 4);
  float* bo1   = (float*)alloc(64 * 4);
  int*   cur   = (int*)alloc((size_t)2 * N * 4);      // [curI | curO]
  int*   offsI = (int*)alloc((size_t)(N + 1) * 4);
  int*   offsO = (int*)alloc((size_t)(N + 1) * 4);
  int2*  eI    = (int2*)alloc((size_t)E * 8);
  int2*  eO    = (int2*)alloc((size_t)E * 8);

  (void)hipMemsetAsync(cur, 0, (size_t)2 * N * 4, stream);

  const int eb = (E + 255) / 256;
  dim3 ge(eb, 2);
  k_hist<<<ge, 256, 0, stream>>>(ei_in, ei_ou, E, cur, N);
  k_scan<<<2, 1024, 0, stream>>>(cur, offsI, offsO, N);
  k_fill<<<ge, 256, 0, stream>>>(ei_in, ew_in, ei_ou, ew_ou, E, cur, eI, eO, N);
  k_wprep<<<(128 * 256 + 255) / 256, 256, 0, stream>>>(Wmi0, Wmo0, Wsh0, Wmi1, Wmo1, Wsh1, resW,
                                                       bmi0, bsi0, bmo0, bso0, bmi1, bsi1, bmo1, bso1,
                                                       Wcat0, Wcat1, bi0, bo0, bi1, bo1);

  int ab = (N + 3) / 4;
  dim3 g0((N + 63) / 64, 4);
  k_gemm<<<g0, 256, 0, stream>>>(x, pe, Wcat0, tbuf, N, 256);
  k_aggL0<<<ab, 256, 0, stream>>>(tbuf, offsI, eI, offsO, eO, bi0, bo0, cin0, cou0, x, pe, hbuf, N);

  dim3 g1((N + 63) / 64, 3);
  k_gemm<<<g1, 256, 0, stream>>>(hbuf, nullptr, Wcat1, tbuf, N, 192);

  float* logp = (float*)d_out;
  float* emb  = logp + (size_t)N * 128;
  k_aggL1<<<ab, 256, 0, stream>>>(tbuf, offsI, eI, offsO, eO, bi1, bo1, resb, cin1, cou1,
                                  hbuf, emb, N);
  k_dec<<<(N + 63) / 64, 256, 0, stream>>>(hbuf, Wd, bd, logp, N);
}

// Round 4
// 535.532 us; speedup vs baseline: 1.4570x; 1.1452x over previous
//
#include <hip/hip_runtime.h>
#include <hip/hip_bf16.h>
#include <math.h>

typedef __hip_bfloat16  bf16;
typedef __hip_bfloat162 bf162;

#define BSZ     128   // nodes per bucket (dst >> 7)
#define NBMAX   512   // max buckets (N <= 65536)
#define PACHUNK 8192  // edges per partA block

// ---------------- CSR build: histogram both edge sets (blockIdx.y selects) ----------------
__global__ void k_hist(const int* __restrict__ eiIn, const int* __restrict__ eiOut,
                       int E, int* __restrict__ cur, int N) {
  int e = blockIdx.x * blockDim.x + threadIdx.x;
  if (e >= E) return;
  const int* ei = blockIdx.y ? eiOut : eiIn;
  atomicAdd(cur + blockIdx.y * N + ei[E + e], 1);
}

__global__ __launch_bounds__(1024) void k_scan(int* cur, int* offsI, int* offsO,
                                               int* bucketCur, int N) {
  int* cnt  = cur + blockIdx.x * N;         // counts in (clobbered)
  int* offs = blockIdx.x ? offsO : offsI;
  __shared__ int wsum[16];
  __shared__ int s_carry, s_total;
  const int t = threadIdx.x, lane = t & 63, wid = t >> 6;
  if (t == 0) s_carry = 0;
  __syncthreads();
  for (int base = 0; base < N; base += 1024) {
    int i = base + t;
    int v = (i < N) ? cnt[i] : 0;
    int incl = v;
    #pragma unroll
    for (int d = 1; d < 64; d <<= 1) {
      int u = __shfl_up(incl, d, 64);
      if (lane >= d) incl += u;
    }
    if (lane == 63) wsum[wid] = incl;
    __syncthreads();
    if (wid == 0) {
      int ws = (lane < 16) ? wsum[lane] : 0;
      int wi = ws;
      #pragma unroll
      for (int d = 1; d < 16; d <<= 1) {
        int u = __shfl_up(wi, d, 64);
        if (lane >= d) wi += u;
      }
      if (lane < 16) wsum[lane] = wi - ws;  // exclusive wave prefix
      if (lane == 15) s_total = wi;
    }
    __syncthreads();
    int excl = s_carry + wsum[wid] + (incl - v);
    if (i < N) { offs[i] = excl; cnt[i] = excl; }
    __syncthreads();
    if (t == 0) s_carry += s_total;
    __syncthreads();
  }
  if (t == 0) offs[N] = s_carry;
  __syncthreads();
  // bucket cursor init: bucket base = offs[b*BSZ] (free from node scan)
  int NB = (N + BSZ - 1) >> 7;
  for (int b = t; b < NB; b += 1024) bucketCur[blockIdx.x * NBMAX + b] = offs[b << 7];
}

// ---------------- partA: counting-sort edges into bucket-contiguous staging ----------------
// pack.x = src(16) | dst_local(7)<<16 | bucket(9)<<23 ; pack.y = f32 weight bits
__global__ __launch_bounds__(256) void k_partA(const int* __restrict__ eiIn, const float* __restrict__ ewIn,
                                               const int* __restrict__ eiOut, const float* __restrict__ ewOut,
                                               int E, int* __restrict__ bucketCur,
                                               int2* __restrict__ sI, int2* __restrict__ sO, int NB) {
  __shared__ int2 staged[PACHUNK];
  __shared__ int cnt[NBMAX];   // counts -> delta (runBase - scanBase)
  __shared__ int sb[NBMAX];    // exclusive scan -> rank cursor
  const int t = threadIdx.x;
  const int set = blockIdx.y;
  const int*   ei = set ? eiOut : eiIn;
  const float* ew = set ? ewOut : ewIn;
  int2* stg  = set ? sO : sI;
  int*  bcur = bucketCur + set * NBMAX;
  const int base = blockIdx.x * PACHUNK;
  const int m = min(PACHUNK, E - base);
  for (int b = t; b < NB; b += 256) cnt[b] = 0;
  __syncthreads();
  #pragma unroll 4
  for (int r = 0; r < PACHUNK / 256; ++r) {
    int i = r * 256 + t;
    if (i < m) atomicAdd(&cnt[ei[E + base + i] >> 7], 1);
  }
  __syncthreads();
  if (t < 64) {  // wave-0 exclusive scan over NB buckets
    int carry = 0;
    int nch = (NB + 63) >> 6;
    for (int c = 0; c < nch; ++c) {
      int idx = c * 64 + t;
      int v = (idx < NB) ? cnt[idx] : 0;
      int incl = v;
      #pragma unroll
      for (int d = 1; d < 64; d <<= 1) {
        int u = __shfl_up(incl, d, 64);
        if (t >= d) incl += u;
      }
      if (idx < NB) sb[idx] = carry + incl - v;
      carry += __shfl(incl, 63, 64);
    }
  }
  __syncthreads();
  for (int b = t; b < NB; b += 256) {
    int c = cnt[b];
    if (c > 0) cnt[b] = atomicAdd(&bcur[b], c) - sb[b];  // delta
  }
  __syncthreads();
  #pragma unroll 4
  for (int r = 0; r < PACHUNK / 256; ++r) {
    int i = r * 256 + t;
    if (i < m) {
      int src = ei[base + i];
      int dst = ei[E + base + i];
      float w = ew[base + i];
      int b = dst >> 7;
      int rank = atomicAdd(&sb[b], 1);
      staged[rank] = make_int2(src | ((dst & 127) << 16) | (b << 23), __float_as_int(w));
    }
  }
  __syncthreads();
  #pragma unroll 4
  for (int r = 0; r < PACHUNK / 256; ++r) {
    int j = r * 256 + t;
    if (j < m) {
      int2 p = staged[j];
      int b = ((unsigned)p.x) >> 23;
      stg[cnt[b] + j] = p;   // gpos = delta[b] + rank(==j); run-contiguous
    }
  }
}

// ---------------- partB: bucket staging -> final CSR order (block-exclusive window) ----------------
__global__ __launch_bounds__(256) void k_partB(const int* __restrict__ offsI, const int* __restrict__ offsO,
                                               const int2* __restrict__ sI, const int2* __restrict__ sO,
                                               int2* __restrict__ eI, int2* __restrict__ eO, int N) {
  __shared__ int cur[BSZ];
  const int t = threadIdx.x;
  const int b = blockIdx.x;
  const int set = blockIdx.y;
  const int*  offs = set ? offsO : offsI;
  const int2* stg  = set ? sO : sI;
  int2* out = set ? eO : eI;
  int nlo = b << 7;
  int cnt = min(BSZ, N - nlo);
  if (t < cnt) cur[t] = offs[nlo + t];
  __syncthreads();
  int lo = offs[nlo], hi = offs[nlo + cnt];
  for (int i = lo + t; i < hi; i += 256) {
    int2 p = stg[i];
    int dl = (p.x >> 16) & 127;
    int pos = atomicAdd(&cur[dl], 1);
    out[pos] = make_int2(p.x & 0xffff, p.y);
  }
}

// ---------------- weight prep: concat weights + pre-combined biases ----------------
__global__ void k_wprep(const float* __restrict__ Wmi0, const float* __restrict__ Wmo0, const float* __restrict__ Ws0,
                        const float* __restrict__ Wmi1, const float* __restrict__ Wmo1, const float* __restrict__ Ws1,
                        const float* __restrict__ resW,
                        const float* __restrict__ bmi0, const float* __restrict__ bsi0,
                        const float* __restrict__ bmo0, const float* __restrict__ bso0,
                        const float* __restrict__ bmi1, const float* __restrict__ bsi1,
                        const float* __restrict__ bmo1, const float* __restrict__ bso1,
                        float* __restrict__ Wcat0, float* __restrict__ Wcat1,
                        float* __restrict__ bi0, float* __restrict__ bo0,
                        float* __restrict__ bi1, float* __restrict__ bo1) {
  int i = blockIdx.x * blockDim.x + threadIdx.x;
  if (i < 128 * 256) {
    int k = i >> 8, n = i & 255;
    float v = (n < 128) ? (Wmi0[k * 128 + n] + Ws0[k * 128 + n])
                        : (Wmo0[k * 128 + n - 128] + Ws0[k * 128 + n - 128]);
    Wcat0[i] = v;
  }
  if (i < 128 * 192) {
    int k = i / 192, n = i % 192;
    float v;
    if (n < 64)       v = Wmi1[k * 64 + n]       + Ws1[k * 64 + n];
    else if (n < 128) v = Wmo1[k * 64 + n - 64]  + Ws1[k * 64 + n - 64];
    else              v = resW[k * 64 + n - 128];
    Wcat1[k * 192 + n] = v;
  }
  if (i < 128) { bi0[i] = bmi0[i] + bsi0[i]; bo0[i] = bmo0[i] + bso0[i]; }
  if (i < 64)  { bi1[i] = bmi1[i] + bsi1[i]; bo1[i] = bmo1[i] + bso1[i]; }
}

// ---------------- GEMM: C_bf16[N x DO] = (A[N x 128] (+pe)) @ W[128 x DO], 64x64 tile ----------------
__global__ __launch_bounds__(256) void k_gemm(const float* __restrict__ A,
                                              const float* __restrict__ pe,  // nullptr if none
                                              const float* __restrict__ W,
                                              bf16* __restrict__ C, int N, int DO) {
  __shared__ float Ast[64][65];  // [k][m] transposed
  __shared__ float Bs[64][68];   // [k][n]
  const int t  = threadIdx.x;
  const int bm = blockIdx.x * 64;
  const int bn = blockIdx.y * 64;
  const int tx = t & 15, ty = t >> 4;
  const int sr = t >> 4;
  const int sc = (t & 15) * 4;
  float acc[4][4] = {};
  for (int kc = 0; kc < 128; kc += 64) {
    __syncthreads();
    #pragma unroll
    for (int j = 0; j < 4; ++j) {
      int r = j * 16 + sr;
      int gm = bm + r;
      float4 v = make_float4(0.f, 0.f, 0.f, 0.f);
      if (gm < N) {
        v = *(const float4*)(A + (size_t)gm * 128 + kc + sc);
        if (pe) {
          float4 p = *(const float4*)(pe + kc + sc);
          v.x += p.x; v.y += p.y; v.z += p.z; v.w += p.w;
        }
      }
      Ast[sc + 0][r] = v.x; Ast[sc + 1][r] = v.y;
      Ast[sc + 2][r] = v.z; Ast[sc + 3][r] = v.w;
      *(float4*)(&Bs[r][sc]) = *(const float4*)(W + (size_t)(kc + r) * DO + bn + sc);
    }
    __syncthreads();
    #pragma unroll 8
    for (int k = 0; k < 64; ++k) {
      float4 a = *(const float4*)(&Ast[k][ty * 4]);
      float4 b = *(const float4*)(&Bs[k][tx * 4]);
      acc[0][0] = fmaf(a.x, b.x, acc[0][0]); acc[0][1] = fmaf(a.x, b.y, acc[0][1]);
      acc[0][2] = fmaf(a.x, b.z, acc[0][2]); acc[0][3] = fmaf(a.x, b.w, acc[0][3]);
      acc[1][0] = fmaf(a.y, b.x, acc[1][0]); acc[1][1] = fmaf(a.y, b.y, acc[1][1]);
      acc[1][2] = fmaf(a.y, b.z, acc[1][2]); acc[1][3] = fmaf(a.y, b.w, acc[1][3]);
      acc[2][0] = fmaf(a.z, b.x, acc[2][0]); acc[2][1] = fmaf(a.z, b.y, acc[2][1]);
      acc[2][2] = fmaf(a.z, b.z, acc[2][2]); acc[2][3] = fmaf(a.z, b.w, acc[2][3]);
      acc[3][0] = fmaf(a.w, b.x, acc[3][0]); acc[3][1] = fmaf(a.w, b.y, acc[3][1]);
      acc[3][2] = fmaf(a.w, b.z, acc[3][2]); acc[3][3] = fmaf(a.w, b.w, acc[3][3]);
    }
  }
  #pragma unroll
  for (int i = 0; i < 4; ++i) {
    int gm = bm + ty * 4 + i;
    if (gm < N) {
      bf162* cp = (bf162*)(C + (size_t)gm * DO + bn + tx * 4);
      cp[0] = __float22bfloat162_rn(make_float2(acc[i][0], acc[i][1]));
      cp[1] = __float22bfloat162_rn(make_float2(acc[i][2], acc[i][3]));
    }
  }
}

// ---------------- layer 0: in-gather + out-gather + epilogue -> h1 (one wave per node) ----------------
__global__ __launch_bounds__(256) void k_aggL0(const bf16* __restrict__ tb,
                                               const int* __restrict__ offsI, const int2* __restrict__ eI,
                                               const int* __restrict__ offsO, const int2* __restrict__ eO,
                                               const float* __restrict__ bi, const float* __restrict__ bo,
                                               const float* __restrict__ cin, const float* __restrict__ cou,
                                               const float* __restrict__ x, const float* __restrict__ pe,
                                               float* __restrict__ h1, int N) {
  int n = (blockIdx.x * blockDim.x + threadIdx.x) >> 6;
  int lane = threadIdx.x & 63;
  if (n >= N) return;
  const int c = lane * 2;
  float a0 = 0.f, a1 = 0.f, b0 = 0.f, b1 = 0.f;
  {
    int s0 = offsI[n], s1 = offsI[n + 1];
    int i = s0;
    for (; i + 3 < s1; i += 4) {
      int2 eA = eI[i], eB = eI[i + 1], eC = eI[i + 2], eD = eI[i + 3];
      float2 vA = __bfloat1622float2(*(const bf162*)(tb + (size_t)eA.x * 256 + c));
      float2 vB = __bfloat1622float2(*(const bf162*)(tb + (size_t)eB.x * 256 + c));
      float2 vC = __bfloat1622float2(*(const bf162*)(tb + (size_t)eC.x * 256 + c));
      float2 vD = __bfloat1622float2(*(const bf162*)(tb + (size_t)eD.x * 256 + c));
      float wA = __int_as_float(eA.y), wB = __int_as_float(eB.y);
      float wC = __int_as_float(eC.y), wD = __int_as_float(eD.y);
      a0 += wA * vA.x + wB * vB.x + wC * vC.x + wD * vD.x;
      a1 += wA * vA.y + wB * vB.y + wC * vC.y + wD * vD.y;
    }
    for (; i < s1; ++i) {
      int2 e = eI[i];
      float2 v = __bfloat1622float2(*(const bf162*)(tb + (size_t)e.x * 256 + c));
      float w = __int_as_float(e.y);
      a0 += w * v.x; a1 += w * v.y;
    }
  }
  {
    int s0 = offsO[n], s1 = offsO[n + 1];
    int i = s0;
    for (; i + 3 < s1; i += 4) {
      int2 eA = eO[i], eB = eO[i + 1], eC = eO[i + 2], eD = eO[i + 3];
      float2 vA = __bfloat1622float2(*(const bf162*)(tb + (size_t)eA.x * 256 + 128 + c));
      float2 vB = __bfloat1622float2(*(const bf162*)(tb + (size_t)eB.x * 256 + 128 + c));
      float2 vC = __bfloat1622float2(*(const bf162*)(tb + (size_t)eC.x * 256 + 128 + c));
      float2 vD = __bfloat1622float2(*(const bf162*)(tb + (size_t)eD.x * 256 + 128 + c));
      float wA = __int_as_float(eA.y), wB = __int_as_float(eB.y);
      float wC = __int_as_float(eC.y), wD = __int_as_float(eD.y);
      b0 += wA * vA.x + wB * vB.x + wC * vC.x + wD * vD.x;
      b1 += wA * vA.y + wB * vB.y + wC * vC.y + wD * vD.y;
    }
    for (; i < s1; ++i) {
      int2 e = eO[i];
      float2 v = __bfloat1622float2(*(const bf162*)(tb + (size_t)e.x * 256 + 128 + c));
      float w = __int_as_float(e.y);
      b0 += w * v.x; b1 += w * v.y;
    }
  }
  float ci = cin[n], co = cou[n];
  float2 bif = *(const float2*)(bi + c);
  float2 bof = *(const float2*)(bo + c);
  float2 x2  = *(const float2*)(x + (size_t)n * 128 + c);
  float2 p2  = *(const float2*)(pe + c);
  float v0 = tanhf(ci * (a0 + bif.x) + co * (b0 + bof.x) + x2.x + p2.x);
  float v1 = tanhf(ci * (a1 + bif.y) + co * (b1 + bof.y) + x2.y + p2.y);
  *(float2*)(h1 + (size_t)n * 128 + c) = make_float2(v0, v1);
}

// ---------------- layer 1: in/out gather (half-wave per edge) + epilogue -> h2, emb ----------------
__global__ __launch_bounds__(256) void k_aggL1(const bf16* __restrict__ t1,
                                               const int* __restrict__ offsI, const int2* __restrict__ eI,
                                               const int* __restrict__ offsO, const int2* __restrict__ eO,
                                               const float* __restrict__ bi, const float* __restrict__ bo,
                                               const float* __restrict__ resb,
                                               const float* __restrict__ cin, const float* __restrict__ cou,
                                               float* __restrict__ h2, float* __restrict__ emb, int N) {
  int n = (blockIdx.x * blockDim.x + threadIdx.x) >> 6;
  int lane = threadIdx.x & 63;
  if (n >= N) return;
  const int sub = lane >> 5;
  const int sl  = lane & 31;
  const int c = sl * 2;
  float a0 = 0.f, a1 = 0.f, b0 = 0.f, b1 = 0.f;
  {
    int s0 = offsI[n], s1 = offsI[n + 1];
    int i = s0 + sub;
    for (; i + 6 < s1; i += 8) {
      int2 eA = eI[i], eB = eI[i + 2], eC = eI[i + 4], eD = eI[i + 6];
      float2 vA = __bfloat1622float2(*(const bf162*)(t1 + (size_t)eA.x * 192 + c));
      float2 vB = __bfloat1622float2(*(const bf162*)(t1 + (size_t)eB.x * 192 + c));
      float2 vC = __bfloat1622float2(*(const bf162*)(t1 + (size_t)eC.x * 192 + c));
      float2 vD = __bfloat1622float2(*(const bf162*)(t1 + (size_t)eD.x * 192 + c));
      float wA = __int_as_float(eA.y), wB = __int_as_float(eB.y);
      float wC = __int_as_float(eC.y), wD = __int_as_float(eD.y);
      a0 += wA * vA.x + wB * vB.x + wC * vC.x + wD * vD.x;
      a1 += wA * vA.y + wB * vB.y + wC * vC.y + wD * vD.y;
    }
    for (; i < s1; i += 2) {
      int2 e = eI[i];
      float2 v = __bfloat1622float2(*(const bf162*)(t1 + (size_t)e.x * 192 + c));
      float w = __int_as_float(e.y);
      a0 += w * v.x; a1 += w * v.y;
    }
  }
  {
    int s0 = offsO[n], s1 = offsO[n + 1];
    int i = s0 + sub;
    for (; i + 6 < s1; i += 8) {
      int2 eA = eO[i], eB = eO[i + 2], eC = eO[i + 4], eD = eO[i + 6];
      float2 vA = __bfloat1622float2(*(const bf162*)(t1 + (size_t)eA.x * 192 + 64 + c));
      float2 vB = __bfloat1622float2(*(const bf162*)(t1 + (size_t)eB.x * 192 + 64 + c));
      float2 vC = __bfloat1622float2(*(const bf162*)(t1 + (size_t)eC.x * 192 + 64 + c));
      float2 vD = __bfloat1622float2(*(const bf162*)(t1 + (size_t)eD.x * 192 + 64 + c));
      float wA = __int_as_float(eA.y), wB = __int_as_float(eB.y);
      float wC = __int_as_float(eC.y), wD = __int_as_float(eD.y);
      b0 += wA * vA.x + wB * vB.x + wC * vC.x + wD * vD.x;
      b1 += wA * vA.y + wB * vB.y + wC * vC.y + wD * vD.y;
    }
    for (; i < s1; i += 2) {
      int2 e = eO[i];
      float2 v = __bfloat1622float2(*(const bf162*)(t1 + (size_t)e.x * 192 + 64 + c));
      float w = __int_as_float(e.y);
      b0 += w * v.x; b1 += w * v.y;
    }
  }
  a0 += __shfl_xor(a0, 32, 64); a1 += __shfl_xor(a1, 32, 64);
  b0 += __shfl_xor(b0, 32, 64); b1 += __shfl_xor(b1, 32, 64);
  float ci = cin[n], co = cou[n];
  float2 bif = *(const float2*)(bi + c);
  float2 bof = *(const float2*)(bo + c);
  float2 rb  = *(const float2*)(resb + c);
  float2 rv  = __bfloat1622float2(*(const bf162*)(t1 + (size_t)n * 192 + 128 + c));
  float v0 = tanhf(ci * (a0 + bif.x) + co * (b0 + bof.x) + rv.x + rb.x);
  float v1 = tanhf(ci * (a1 + bif.y) + co * (b1 + bof.y) + rv.y + rb.y);
  float q = v0 * v0 + v1 * v1;
  #pragma unroll
  for (int d = 16; d > 0; d >>= 1) q += __shfl_xor(q, d, 64);
  float inv = 1.0f / (sqrtf(q) + 1e-12f);
  if (sub == 0) {
    *(float2*)(h2  + (size_t)n * 64 + c) = make_float2(v0, v1);
    *(float2*)(emb + (size_t)n * 64 + c) = make_float2(v0 * inv, v1 * inv);
  }
}

// ---------------- decoder as register-tiled GEMM + fused log_softmax ----------------
__global__ __launch_bounds__(256) void k_dec(const float* __restrict__ h2,
                                             const float* __restrict__ Wd, const float* __restrict__ bd,
                                             float* __restrict__ logp, int N) {
  __shared__ float Ht[64][65];
  __shared__ float Bs[64][132];
  __shared__ float sb[128];
  const int t  = threadIdx.x;
  const int bm = blockIdx.x * 64;
  const int tx = t & 15, ty = t >> 4;
  const int sr = t >> 4;
  const int sc = (t & 15) * 4;
  #pragma unroll
  for (int j = 0; j < 4; ++j) {
    int r = j * 16 + sr;
    int gm = bm + r;
    float4 v = make_float4(0.f, 0.f, 0.f, 0.f);
    if (gm < N) v = *(const float4*)(h2 + (size_t)gm * 64 + sc);
    Ht[sc + 0][r] = v.x; Ht[sc + 1][r] = v.y;
    Ht[sc + 2][r] = v.z; Ht[sc + 3][r] = v.w;
    const float* wrow = Wd + (size_t)r * 128 + tx * 8;
    *(float4*)(&Bs[r][tx * 8])     = *(const float4*)(wrow);
    *(float4*)(&Bs[r][tx * 8 + 4]) = *(const float4*)(wrow + 4);
  }
  if (t < 128) sb[t] = bd[t];
  __syncthreads();
  float acc[4][8] = {};
  #pragma unroll 8
  for (int k = 0; k < 64; ++k) {
    float4 a  = *(const float4*)(&Ht[k][ty * 4]);
    float4 b0 = *(const float4*)(&Bs[k][tx * 4]);
    float4 b1 = *(const float4*)(&Bs[k][64 + tx * 4]);
    acc[0][0] = fmaf(a.x, b0.x, acc[0][0]); acc[0][1] = fmaf(a.x, b0.y, acc[0][1]);
    acc[0][2] = fmaf(a.x, b0.z, acc[0][2]); acc[0][3] = fmaf(a.x, b0.w, acc[0][3]);
    acc[0][4] = fmaf(a.x, b1.x, acc[0][4]); acc[0][5] = fmaf(a.x, b1.y, acc[0][5]);
    acc[0][6] = fmaf(a.x, b1.z, acc[0][6]); acc[0][7] = fmaf(a.x, b1.w, acc[0][7]);
    acc[1][0] = fmaf(a.y, b0.x, acc[1][0]); acc[1][1] = fmaf(a.y, b0.y, acc[1][1]);
    acc[1][2] = fmaf(a.y, b0.z, acc[1][2]); acc[1][3] = fmaf(a.y, b0.w, acc[1][3]);
    acc[1][4] = fmaf(a.y, b1.x, acc[1][4]); acc[1][5] = fmaf(a.y, b1.y, acc[1][5]);
    acc[1][6] = fmaf(a.y, b1.z, acc[1][6]); acc[1][7] = fmaf(a.y, b1.w, acc[1][7]);
    acc[2][0] = fmaf(a.z, b0.x, acc[2][0]); acc[2][1] = fmaf(a.z, b0.y, acc[2][1]);
    acc[2][2] = fmaf(a.z, b0.z, acc[2][2]); acc[2][3] = fmaf(a.z, b0.w, acc[2][3]);
    acc[2][4] = fmaf(a.z, b1.x, acc[2][4]); acc[2][5] = fmaf(a.z, b1.y, acc[2][5]);
    acc[2][6] = fmaf(a.z, b1.z, acc[2][6]); acc[2][7] = fmaf(a.z, b1.w, acc[2][7]);
    acc[3][0] = fmaf(a.w, b0.x, acc[3][0]); acc[3][1] = fmaf(a.w, b0.y, acc[3][1]);
    acc[3][2] = fmaf(a.w, b0.z, acc[3][2]); acc[3][3] = fmaf(a.w, b0.w, acc[3][3]);
    acc[3][4] = fmaf(a.w, b1.x, acc[3][4]); acc[3][5] = fmaf(a.w, b1.y, acc[3][5]);
    acc[3][6] = fmaf(a.w, b1.z, acc[3][6]); acc[3][7] = fmaf(a.w, b1.w, acc[3][7]);
  }
  float bb[8];
  #pragma unroll
  for (int j = 0; j < 4; ++j) { bb[j] = sb[tx * 4 + j]; bb[4 + j] = sb[64 + tx * 4 + j]; }
  #pragma unroll
  for (int i = 0; i < 4; ++i) {
    int gm = bm + ty * 4 + i;
    float v[8];
    #pragma unroll
    for (int j = 0; j < 8; ++j) v[j] = acc[i][j] + bb[j];
    float m = v[0];
    #pragma unroll
    for (int j = 1; j < 8; ++j) m = fmaxf(m, v[j]);
    #pragma unroll
    for (int d = 1; d < 16; d <<= 1) m = fmaxf(m, __shfl_xor(m, d, 64));
    float s = 0.f;
    #pragma unroll
    for (int j = 0; j < 8; ++j) s += __expf(v[j] - m);
    #pragma unroll
    for (int d = 1; d < 16; d <<= 1) s += __shfl_xor(s, d, 64);
    float lse = m + __logf(s);
    if (gm < N) {
      float4 o0 = make_float4(v[0] - lse, v[1] - lse, v[2] - lse, v[3] - lse);
      float4 o1 = make_float4(v[4] - lse, v[5] - lse, v[6] - lse, v[7] - lse);
      *(float4*)(logp + (size_t)gm * 128 + tx * 4)      = o0;
      *(float4*)(logp + (size_t)gm * 128 + 64 + tx * 4) = o1;
    }
  }
}

extern "C" void kernel_launch(void* const* d_in, const int* in_sizes, int n_in,
                              void* d_out, int out_size, void* d_ws, size_t ws_size,
                              hipStream_t stream) {
  const float* x     = (const float*)d_in[0];
  const int*   ei_in = (const int*)d_in[1];
  const float* ew_in = (const float*)d_in[2];
  const int*   ei_ou = (const int*)d_in[3];
  const float* ew_ou = (const float*)d_in[4];
  const float* pe    = (const float*)d_in[5];
  const float* Wmi0  = (const float*)d_in[6];
  const float* Wmo0  = (const float*)d_in[7];
  const float* Wsh0  = (const float*)d_in[8];
  const float* bmi0  = (const float*)d_in[9];
  const float* bmo0  = (const float*)d_in[10];
  const float* bsi0  = (const float*)d_in[11];
  const float* bso0  = (const float*)d_in[12];
  const float* cin0  = (const float*)d_in[13];
  const float* cou0  = (const float*)d_in[14];
  const float* Wmi1  = (const float*)d_in[15];
  const float* Wmo1  = (const float*)d_in[16];
  const float* Wsh1  = (const float*)d_in[17];
  const float* bmi1  = (const float*)d_in[18];
  const float* bmo1  = (const float*)d_in[19];
  const float* bsi1  = (const float*)d_in[20];
  const float* bso1  = (const float*)d_in[21];
  const float* cin1  = (const float*)d_in[22];
  const float* cou1  = (const float*)d_in[23];
  const float* resW  = (const float*)d_in[24];
  const float* resb  = (const float*)d_in[25];
  const float* Wd    = (const float*)d_in[26];
  const float* bd    = (const float*)d_in[27];

  const int N = in_sizes[0] / 128;
  const int E = in_sizes[2];
  const int NB = (N + BSZ - 1) >> 7;

  char* ws = (char*)d_ws;
  size_t off = 0;
  auto alloc = [&](size_t bytes) -> char* {
    off = (off + 255) & ~(size_t)255;
    char* p = ws + off;
    off += bytes;
    return p;
  };
  bf16*  tbuf  = (bf16*)alloc((size_t)N * 256 * 2);   // t0 (N x 256 bf16) -> t1 (N x 192 bf16)
  float* hbuf  = (float*)alloc((size_t)N * 128 * 4);  // h1 -> h2 (overlay, N x 64)
  float* Wcat0 = (float*)alloc(128 * 256 * 4);
  float* Wcat1 = (float*)alloc(128 * 192 * 4);
  float* bi0   = (float*)alloc(128 * 4);
  float* bo0   = (float*)alloc(128 * 4);
  float* bi1   = (float*)alloc(64 * 4);
  float* bo1   = (float*)alloc(64 * 4);
  int*   cur   = (int*)alloc((size_t)2 * N * 4);      // [cntI | cntO] for node hist
  int*   offsI = (int*)alloc((size_t)(N + 1) * 4);
  int*   offsO = (int*)alloc((size_t)(N + 1) * 4);
  int*   bcur  = (int*)alloc((size_t)2 * NBMAX * 4);  // bucket cursors
  int2*  sI    = (int2*)alloc((size_t)E * 8);         // bucket staging
  int2*  sO    = (int2*)alloc((size_t)E * 8);
  int2*  eI    = (int2*)alloc((size_t)E * 8);         // final CSR edges
  int2*  eO    = (int2*)alloc((size_t)E * 8);

  (void)hipMemsetAsync(cur, 0, (size_t)2 * N * 4, stream);

  const int eb = (E + 255) / 256;
  dim3 ge(eb, 2);
  k_hist<<<ge, 256, 0, stream>>>(ei_in, ei_ou, E, cur, N);
  k_scan<<<2, 1024, 0, stream>>>(cur, offsI, offsO, bcur, N);
  dim3 gp((E + PACHUNK - 1) / PACHUNK, 2);
  k_partA<<<gp, 256, 0, stream>>>(ei_in, ew_in, ei_ou, ew_ou, E, bcur, sI, sO, NB);
  dim3 gb(NB, 2);
  k_partB<<<gb, 256, 0, stream>>>(offsI, offsO, sI, sO, eI, eO, N);
  k_wprep<<<(128 * 256 + 255) / 256, 256, 0, stream>>>(Wmi0, Wmo0, Wsh0, Wmi1, Wmo1, Wsh1, resW,
                                                       bmi0, bsi0, bmo0, bso0, bmi1, bsi1, bmo1, bso1,
                                                       Wcat0, Wcat1, bi0, bo0, bi1, bo1);

  int ab = (N + 3) / 4;
  dim3 g0((N + 63) / 64, 4);
  k_gemm<<<g0, 256, 0, stream>>>(x, pe, Wcat0, tbuf, N, 256);
  k_aggL0<<<ab, 256, 0, stream>>>(tbuf, offsI, eI, offsO, eO, bi0, bo0, cin0, cou0, x, pe, hbuf, N);

  dim3 g1((N + 63) / 64, 3);
  k_gemm<<<g1, 256, 0, stream>>>(hbuf, nullptr, Wcat1, tbuf, N, 192);

  float* logp = (float*)d_out;
  float* emb  = logp + (size_t)N * 128;
  k_aggL1<<<ab, 256, 0, stream>>>(tbuf, offsI, eI, offsO, eO, bi1, bo1, resb, cin1, cou1,
                                  hbuf, emb, N);
  k_dec<<<(N + 63) / 64, 256, 0, stream>>>(hbuf, Wd, bd, logp, N);
}